// Round 1
// 623.880 us; speedup vs baseline: 1.1183x; 1.1183x over previous
//
#include <hip/hip_runtime.h>
#include <math.h>

// Problem constants (fixed by setup_inputs)
#define Bb 8
#define Cc 192
#define NHEADS 8
#define HDim 24
#define Him 128
#define Wim 128
#define Ntok 16384   // H*W
#define EPSBN 1e-5f

typedef __bf16 bf16x8 __attribute__((ext_vector_type(8)));
typedef float  f32x4  __attribute__((ext_vector_type(4)));

static __device__ __forceinline__ float gelu_f(float v) {
    return 0.5f * v * (1.0f + erff(v * 0.70710678118654752f));
}
static __device__ __forceinline__ float sigmoid_f(float v) {
    return 1.0f / (1.0f + expf(-v));
}
static __device__ __forceinline__ void split8(const float* xv, bf16x8& h8, bf16x8& l8) {
#pragma unroll
    for (int j = 0; j < 8; ++j) {
        float v = xv[j];
        __bf16 h = (__bf16)v;
        h8[j] = h;
        l8[j] = (__bf16)(v - (float)h);
    }
}
static __device__ __forceinline__ void ld8(const float* p, float* v) {
    float4 u0 = *(const float4*)p, u1 = *(const float4*)(p + 4);
    v[0] = u0.x; v[1] = u0.y; v[2] = u0.z; v[3] = u0.w;
    v[4] = u1.x; v[5] = u1.y; v[6] = u1.z; v[7] = u1.w;
}

// ---------------------------------------------------------------------------
// K0: one-time prep: transpose w_qkv (192x576 fp32) into bf16 hi/lo planes in
// [col][k] layout. Stored in tail of d_out (dead until k_final's final write).
// ---------------------------------------------------------------------------
__global__ __launch_bounds__(256) void k_wprep(const float* __restrict__ w,
                                               __bf16* __restrict__ wt)
{
    int idx = blockIdx.x * 256 + threadIdx.x;   // 192*576 = 110592 total
    if (idx >= 192 * 576) return;
    int k = idx / 576, c = idx % 576;           // coalesced read over c
    float v = w[idx];
    __bf16 h = (__bf16)v;
    __bf16 l = (__bf16)(v - (float)h);
    wt[c * 192 + k] = h;
    wt[110592 + c * 192 + k] = l;
}

// ---------------------------------------------------------------------------
// K1: qkv projection via split-bf16 MFMA. Block = 128 tokens x 192 cols of
// section sec. Output transposed to (B,C,N). v-section blocks also
// accumulate per-channel sums (replaces k_vmean).
// ---------------------------------------------------------------------------
__global__ __launch_bounds__(256, 2) void k_qkv_mfma(const float* __restrict__ x,
                                                     const __bf16* __restrict__ wt,
                                                     float* __restrict__ qkv,
                                                     float* __restrict__ vsum)
{
    __shared__ __align__(16) __bf16 Ah[128 * 40];
    __shared__ __align__(16) __bf16 Al[128 * 40];
    __shared__ __align__(16) __bf16 Bh[192 * 40];
    __shared__ __align__(16) __bf16 Bl[192 * 40];

    const int t = threadIdx.x;
    const int lane = t & 63, wave = t >> 6;
    const int n0 = blockIdx.x * 128;
    const int b = blockIdx.y;
    const int sec = blockIdx.z;
    const int row_base = (wave & 1) * 64;
    const int col_base = (wave >> 1) * 96;
    const int m16 = lane & 15, q = lane >> 4;

    f32x4 acc[4][6];
#pragma unroll
    for (int rt = 0; rt < 4; ++rt)
#pragma unroll
        for (int ct = 0; ct < 6; ++ct)
#pragma unroll
            for (int j = 0; j < 4; ++j) acc[rt][ct][j] = 0.f;

    const int ar = t >> 1, ahalf = t & 1;
    const float* xrow = x + ((size_t)b * Ntok + n0 + ar) * Cc + ahalf * 16;

    for (int kc = 0; kc < 6; ++kc) {
        {
            const float4* xp4 = (const float4*)(xrow + kc * 32);
            float xv[16];
            float4 u;
            u = xp4[0]; xv[0] = u.x; xv[1] = u.y; xv[2]  = u.z; xv[3]  = u.w;
            u = xp4[1]; xv[4] = u.x; xv[5] = u.y; xv[6]  = u.z; xv[7]  = u.w;
            u = xp4[2]; xv[8] = u.x; xv[9] = u.y; xv[10] = u.z; xv[11] = u.w;
            u = xp4[3]; xv[12] = u.x; xv[13] = u.y; xv[14] = u.z; xv[15] = u.w;
            bf16x8 vh0, vh1, vl0, vl1;
            split8(xv, vh0, vl0);
            split8(xv + 8, vh1, vl1);
            const int o = ar * 40 + ahalf * 16;
            *(bf16x8*)&Ah[o] = vh0; *(bf16x8*)&Ah[o + 8] = vh1;
            *(bf16x8*)&Al[o] = vl0; *(bf16x8*)&Al[o + 8] = vl1;
        }
#pragma unroll
        for (int i = 0; i < 3; ++i) {
            int f = i * 256 + t;
            int n = f >> 2, k8 = (f & 3) << 3;
            const __bf16* src = wt + ((size_t)(sec * 192 + n)) * 192 + kc * 32 + k8;
            bf16x8 vh = *(const bf16x8*)src;
            bf16x8 vl = *(const bf16x8*)(src + 110592);
            *(bf16x8*)&Bh[n * 40 + k8] = vh;
            *(bf16x8*)&Bl[n * 40 + k8] = vl;
        }
        __syncthreads();

        bf16x8 fah[4], fal[4], fbh[6], fbl[6];
#pragma unroll
        for (int rt = 0; rt < 4; ++rt) {
            int o = (row_base + rt * 16 + m16) * 40 + q * 8;
            fah[rt] = *(const bf16x8*)&Ah[o];
            fal[rt] = *(const bf16x8*)&Al[o];
        }
#pragma unroll
        for (int ct = 0; ct < 6; ++ct) {
            int o = (col_base + ct * 16 + m16) * 40 + q * 8;
            fbh[ct] = *(const bf16x8*)&Bh[o];
            fbl[ct] = *(const bf16x8*)&Bl[o];
        }
#pragma unroll
        for (int rt = 0; rt < 4; ++rt)
#pragma unroll
            for (int ct = 0; ct < 6; ++ct) {
                acc[rt][ct] = __builtin_amdgcn_mfma_f32_16x16x32_bf16(
                    fah[rt], fbh[ct], acc[rt][ct], 0, 0, 0);
                acc[rt][ct] = __builtin_amdgcn_mfma_f32_16x16x32_bf16(
                    fah[rt], fbl[ct], acc[rt][ct], 0, 0, 0);
                acc[rt][ct] = __builtin_amdgcn_mfma_f32_16x16x32_bf16(
                    fal[rt], fbh[ct], acc[rt][ct], 0, 0, 0);
            }
        __syncthreads();
    }

    const size_t obase = (size_t)sec * ((size_t)Bb * Cc * Ntok)
                       + (size_t)b * Cc * (size_t)Ntok;
#pragma unroll
    for (int rt = 0; rt < 4; ++rt)
#pragma unroll
        for (int ct = 0; ct < 6; ++ct) {
            int token = n0 + row_base + rt * 16 + q * 4;
            int col = col_base + ct * 16 + m16;
            float4 o = make_float4(acc[rt][ct][0], acc[rt][ct][1],
                                   acc[rt][ct][2], acc[rt][ct][3]);
            *(float4*)(qkv + obase + (size_t)col * Ntok + token) = o;
        }

    if (sec == 2) {
#pragma unroll
        for (int ct = 0; ct < 6; ++ct) {
            float s = 0.f;
#pragma unroll
            for (int rt = 0; rt < 4; ++rt)
                s += acc[rt][ct][0] + acc[rt][ct][1] + acc[rt][ct][2] + acc[rt][ct][3];
            s += __shfl_xor(s, 16, 64);
            s += __shfl_xor(s, 32, 64);
            if (q == 0)
                atomicAdd(vsum + b * Cc + col_base + ct * 16 + m16, s);
        }
    }
}

// ---------------------------------------------------------------------------
// K2 v2 (MFMA): Gram + sum-of-squares via split-bf16 MFMA, fragments loaded
// straight from global (no LDS). One head per wave, 4 heads per block,
// 512-token chunk per block; grid (32, 2, B) = 512 blocks.
// D-layout (verified mapping): row(q-chan) = (lane>>4)*4+j, col(k-chan)=lane&15.
// Channels 0-15 in tile1; 16-23 zero-padded in tile2.
// ---------------------------------------------------------------------------
__global__ __launch_bounds__(256) void k_gram(const float* __restrict__ qbuf,
                                              const float* __restrict__ kbuf,
                                              float* __restrict__ gram,
                                              float* __restrict__ ssq_q,
                                              float* __restrict__ ssq_k)
{
    const int t = threadIdx.x;
    const int lane = t & 63, wave = t >> 6;
    const int chunk = blockIdx.x;          // 32 chunks of 512 tokens
    const int hg = blockIdx.y;             // head group (0/1)
    const int b = blockIdx.z;
    const int h = hg * 4 + wave;           // one head per wave
    const int row = lane & 15, tg = lane >> 4;
    const bool r2v = row < 8;

    const size_t hb = ((size_t)b * Cc + h * HDim) * Ntok + chunk * 512 + tg * 8;
    const float* q1 = qbuf + hb + (size_t)row * Ntok;
    const float* k1 = kbuf + hb + (size_t)row * Ntok;
    const float* q2 = qbuf + hb + (size_t)(16 + row) * Ntok;   // valid iff r2v
    const float* k2 = kbuf + hb + (size_t)(16 + row) * Ntok;

    f32x4 acc[2][2];
#pragma unroll
    for (int rt = 0; rt < 2; ++rt)
#pragma unroll
        for (int ct = 0; ct < 2; ++ct)
#pragma unroll
            for (int j = 0; j < 4; ++j) acc[rt][ct][j] = 0.f;
    float sq1 = 0.f, sq2 = 0.f, sk1 = 0.f, sk2 = 0.f;

    for (int s = 0; s < 16; ++s) {
        const int off = s * 32;
        float xq1[8], xq2[8], xk1[8], xk2[8];
        ld8(q1 + off, xq1);
        ld8(k1 + off, xk1);
        if (r2v) {
            ld8(q2 + off, xq2);
            ld8(k2 + off, xk2);
        } else {
#pragma unroll
            for (int j = 0; j < 8; ++j) { xq2[j] = 0.f; xk2[j] = 0.f; }
        }
#pragma unroll
        for (int j = 0; j < 8; ++j) {
            sq1 = fmaf(xq1[j], xq1[j], sq1);
            sk1 = fmaf(xk1[j], xk1[j], sk1);
            sq2 = fmaf(xq2[j], xq2[j], sq2);
            sk2 = fmaf(xk2[j], xk2[j], sk2);
        }
        bf16x8 q1h, q1l, q2h, q2l, k1h, k1l, k2h, k2l;
        split8(xq1, q1h, q1l);
        split8(xq2, q2h, q2l);
        split8(xk1, k1h, k1l);
        split8(xk2, k2h, k2l);

        acc[0][0] = __builtin_amdgcn_mfma_f32_16x16x32_bf16(q1h, k1h, acc[0][0], 0, 0, 0);
        acc[0][0] = __builtin_amdgcn_mfma_f32_16x16x32_bf16(q1h, k1l, acc[0][0], 0, 0, 0);
        acc[0][0] = __builtin_amdgcn_mfma_f32_16x16x32_bf16(q1l, k1h, acc[0][0], 0, 0, 0);

        acc[0][1] = __builtin_amdgcn_mfma_f32_16x16x32_bf16(q1h, k2h, acc[0][1], 0, 0, 0);
        acc[0][1] = __builtin_amdgcn_mfma_f32_16x16x32_bf16(q1h, k2l, acc[0][1], 0, 0, 0);
        acc[0][1] = __builtin_amdgcn_mfma_f32_16x16x32_bf16(q1l, k2h, acc[0][1], 0, 0, 0);

        acc[1][0] = __builtin_amdgcn_mfma_f32_16x16x32_bf16(q2h, k1h, acc[1][0], 0, 0, 0);
        acc[1][0] = __builtin_amdgcn_mfma_f32_16x16x32_bf16(q2h, k1l, acc[1][0], 0, 0, 0);
        acc[1][0] = __builtin_amdgcn_mfma_f32_16x16x32_bf16(q2l, k1h, acc[1][0], 0, 0, 0);

        acc[1][1] = __builtin_amdgcn_mfma_f32_16x16x32_bf16(q2h, k2h, acc[1][1], 0, 0, 0);
        acc[1][1] = __builtin_amdgcn_mfma_f32_16x16x32_bf16(q2h, k2l, acc[1][1], 0, 0, 0);
        acc[1][1] = __builtin_amdgcn_mfma_f32_16x16x32_bf16(q2l, k2h, acc[1][1], 0, 0, 0);
    }

    // sum-of-squares: reduce over the 4 token-groups (lanes row, row+16, +32, +48)
    sq1 += __shfl_xor(sq1, 16, 64); sq1 += __shfl_xor(sq1, 32, 64);
    sk1 += __shfl_xor(sk1, 16, 64); sk1 += __shfl_xor(sk1, 32, 64);
    sq2 += __shfl_xor(sq2, 16, 64); sq2 += __shfl_xor(sq2, 32, 64);
    sk2 += __shfl_xor(sk2, 16, 64); sk2 += __shfl_xor(sk2, 32, 64);
    if (tg == 0) {
        atomicAdd(ssq_q + b * Cc + h * HDim + row, sq1);
        atomicAdd(ssq_k + b * Cc + h * HDim + row, sk1);
        if (r2v) {
            atomicAdd(ssq_q + b * Cc + h * HDim + 16 + row, sq2);
            atomicAdd(ssq_k + b * Cc + h * HDim + 16 + row, sk2);
        }
    }

    float* gp = gram + (size_t)(b * NHEADS + h) * 576;
#pragma unroll
    for (int rt = 0; rt < 2; ++rt)
#pragma unroll
        for (int ct = 0; ct < 2; ++ct)
#pragma unroll
            for (int j = 0; j < 4; ++j) {
                int qc = rt * 16 + tg * 4 + j;      // q channel (D row)
                int kc = ct * 16 + row;             // k channel (D col)
                if (qc < 24 && kc < 24)
                    atomicAdd(gp + qc * 24 + kc, acc[rt][ct][j]);
            }
}

// K4: normalize gram -> softmax attn; pooled = attn @ vmean; channel-gate MLP.
__global__ __launch_bounds__(256) void k_attn(const float* __restrict__ gram,
                                              const float* __restrict__ ssq_q,
                                              const float* __restrict__ ssq_k,
                                              const float* __restrict__ temperature,
                                              const float* __restrict__ vmean,
                                              const float* __restrict__ ci_w1,
                                              const float* __restrict__ ci_b1,
                                              const float* __restrict__ bn2_g,
                                              const float* __restrict__ bn2_b,
                                              const float* __restrict__ bn2_m,
                                              const float* __restrict__ bn2_v,
                                              const float* __restrict__ ci_w2,
                                              const float* __restrict__ ci_b2,
                                              float* __restrict__ attn,
                                              float* __restrict__ sig_ch)
{
    __shared__ float pooled[192];
    __shared__ float cmv[24];
    const int b = blockIdx.x, t = threadIdx.x;
    if (t < 192) {
        int h = t / 24, c = t % 24;
        const float* gp = gram + (size_t)(b * NHEADS + h) * 576 + c * 24;
        float qn = fmaxf(sqrtf(ssq_q[b * Cc + h * HDim + c]), 1e-12f);
        float temp = temperature[h];
        float logit[24];
        float m = -1e30f;
#pragma unroll
        for (int d = 0; d < 24; ++d) {
            float kn = fmaxf(sqrtf(ssq_k[b * Cc + h * HDim + d]), 1e-12f);
            float l = gp[d] / (qn * kn) * temp;
            logit[d] = l; m = fmaxf(m, l);
        }
        float s = 0.f;
#pragma unroll
        for (int d = 0; d < 24; ++d) { float e = expf(logit[d] - m); logit[d] = e; s += e; }
        float inv = 1.f / s;
        float pool = 0.f;
        float* ap = attn + (size_t)(b * NHEADS + h) * 576 + c * 24;
#pragma unroll
        for (int d = 0; d < 24; ++d) {
            float a = logit[d] * inv;
            ap[d] = a;
            pool = fmaf(a, vmean[b * Cc + h * HDim + d], pool);
        }
        pooled[h * 24 + c] = pool * (1.0f / (float)Ntok);
    }
    __syncthreads();
    if (t < 24) {
        float z = ci_b1[t];
        for (int c = 0; c < 192; ++c) z = fmaf(ci_w1[t * 192 + c], pooled[c], z);
        float sc = bn2_g[t] / sqrtf(bn2_v[t] + EPSBN);
        z = z * sc + (bn2_b[t] - bn2_m[t] * sc);
        cmv[t] = gelu_f(z);
    }
    __syncthreads();
    if (t < 192) {
        float z = ci_b2[t];
#pragma unroll
        for (int o = 0; o < 24; ++o) z = fmaf(ci_w2[t * 24 + o], cmv[o], z);
        sig_ch[b * Cc + t] = sigmoid_f(z);
    }
}

// ---------------------------------------------------------------------------
// K4b: fold attention + channel gate into projection (see round 2 notes).
// ---------------------------------------------------------------------------
__global__ __launch_bounds__(192) void k_pprep(const float* __restrict__ attn,
                                               const float* __restrict__ sig_ch,
                                               const float* __restrict__ proj_w,
                                               __bf16* __restrict__ Pt)
{
    const int b = blockIdx.x, part = blockIdx.y, j = threadIdx.x;
    __bf16* base = Pt + (size_t)b * (2 * 73728);   // 73728 = 192*384
    if (part < 8) {
        const int h = part;
        __shared__ float at[576];
        for (int e = j; e < 576; e += 192) at[e] = attn[(size_t)(b * 8 + h) * 576 + e];
        __syncthreads();
        float pr[24];
#pragma unroll
        for (int cl = 0; cl < 24; ++cl) pr[cl] = proj_w[(h * 24 + cl) * 192 + j];
        float s[24];
#pragma unroll
        for (int d = 0; d < 24; ++d) s[d] = 0.f;
#pragma unroll
        for (int cl = 0; cl < 24; ++cl) {
            float a = pr[cl];
#pragma unroll
            for (int d = 0; d < 24; ++d) s[d] = fmaf(a, at[cl * 24 + d], s[d]);
        }
#pragma unroll
        for (int d = 0; d < 24; ++d) {
            float v = s[d];
            __bf16 hi = (__bf16)v;
            base[j * 384 + h * 24 + d] = hi;
            base[73728 + j * 384 + h * 24 + d] = (__bf16)(v - (float)hi);
        }
    } else {
        __shared__ float sch_s[192];
        sch_s[j] = sig_ch[b * Cc + j];
        __syncthreads();
        for (int ch = 0; ch < 192; ++ch) {
            float v = sch_s[ch] * proj_w[ch * 192 + j];
            __bf16 hi = (__bf16)v;
            base[j * 384 + 192 + ch] = hi;
            base[73728 + j * 384 + 192 + ch] = (__bf16)(v - (float)hi);
        }
    }
}

// ---------------------------------------------------------------------------
// K5 v2 (FIXED): depthwise 3x3 conv + BN1 + GELU. Block = 8 rows x 128 px x
// 8 ch; grid (16, 24, B) = 3072 blocks.
// ---------------------------------------------------------------------------
__global__ __launch_bounds__(256) void k_conv(const float* __restrict__ vbuf,
                                              const float* __restrict__ dw_w,
                                              const float* __restrict__ dw_b,
                                              const float* __restrict__ bn1_g,
                                              const float* __restrict__ bn1_b,
                                              const float* __restrict__ bn1_m,
                                              const float* __restrict__ bn1_v,
                                              float* __restrict__ convx)
{
    __shared__ float vh[8][10][130];   // 8 ch x 10 rows x (1 | 128 | 1) pad cols
    __shared__ float dww[8 * 9];
    __shared__ float scl[8], shf[8];
    const int t = threadIdx.x;
    const int y0 = blockIdx.x * 8;
    const int ch0 = blockIdx.y * 8;
    const int b = blockIdx.z;

    if (t < 72) {
        dww[t] = dw_w[ch0 * 9 + t];
    } else if (t < 80) {
        int c = t - 72, ch = ch0 + c;
        float sc = bn1_g[ch] / sqrtf(bn1_v[ch] + EPSBN);
        scl[c] = sc;
        shf[c] = (dw_b[ch] - bn1_m[ch]) * sc + bn1_b[ch];
    } else if (t < 160) {
        int e = t - 80;                 // zero the x-pad columns
        int ch = e / 10, r = e % 10;
        vh[ch][r][0] = 0.f;
        vh[ch][r][129] = 0.f;
    }
    // stage 8ch x 10 rows x 128 cols (rows y0-1 .. y0+8), coalesced full rows
    for (int e = t; e < 8 * 10 * 128; e += 256) {
        int ch = e / 1280, rem = e - ch * 1280;
        int r = rem >> 7, xc = rem & 127;
        int gy = y0 - 1 + r;
        float v = 0.f;
        if (gy >= 0 && gy < Him)
            v = vbuf[((size_t)b * Cc + ch0 + ch) * Ntok + gy * Wim + xc];
        vh[ch][r][xc + 1] = v;
    }
    __syncthreads();

    const int xc = t & 127, half = t >> 7;   // half: rows 0-3 / 4-7
#pragma unroll
    for (int ch = 0; ch < 8; ++ch) {
        const float w0 = dww[ch * 9 + 0], w1 = dww[ch * 9 + 1], w2 = dww[ch * 9 + 2];
        const float w3 = dww[ch * 9 + 3], w4 = dww[ch * 9 + 4], w5 = dww[ch * 9 + 5];
        const float w6 = dww[ch * 9 + 6], w7 = dww[ch * 9 + 7], w8 = dww[ch * 9 + 8];
        const float sc = scl[ch], sh = shf[ch];
        float* op = convx + ((size_t)b * Cc + ch0 + ch) * Ntok + (size_t)y0 * Wim + xc;
#pragma unroll
        for (int rr = 0; rr < 4; ++rr) {
            int r = half * 4 + rr;               // output row within tile
            const float* r0 = &vh[ch][r][xc];    // source rows r, r+1, r+2
            const float* r1 = &vh[ch][r + 1][xc];
            const float* r2 = &vh[ch][r + 2][xc];
            float conv = r0[0] * w0 + r0[1] * w1 + r0[2] * w2
                       + r1[0] * w3 + r1[1] * w4 + r1[2] * w5
                       + r2[0] * w6 + r2[1] * w7 + r2[2] * w8;
            op[(size_t)r * Wim] = gelu_f(conv * sc + sh);
        }
    }
}

// ---------------------------------------------------------------------------
// K6 v2: fused epilogue GEMM + spatial-gate MLP.
// Phase 0 (kc 6..11): A = convx chunks; MFMA vs P_conv AND vs si_w1^T (extra
//   16-col tile, lanes>=12 zero) -> first-layer sums in C-layout.
// Gate: dump to padded LDS, 128 threads do BN3+GELU+w2+sigmoid -> ssp_s.
// Phase 1 (kc 0..5): A = v chunks scaled by ssp_s[token]; MFMA vs P_att.
// ---------------------------------------------------------------------------
__global__ __launch_bounds__(256, 2) void k_final_mfma(const float* __restrict__ vbuf,
                                                       const float* __restrict__ convx,
                                                       const __bf16* __restrict__ Pt,
                                                       const float* __restrict__ si_w1,
                                                       const float* __restrict__ si_b1,
                                                       const float* __restrict__ bn3_g,
                                                       const float* __restrict__ bn3_b,
                                                       const float* __restrict__ bn3_m,
                                                       const float* __restrict__ bn3_v,
                                                       const float* __restrict__ si_w2,
                                                       const float* __restrict__ si_b2,
                                                       const float* __restrict__ proj_b,
                                                       float* __restrict__ out)
{
    __shared__ __align__(16) __bf16 Ah[128 * 40];
    __shared__ __align__(16) __bf16 Al[128 * 40];
    __shared__ __align__(16) __bf16 Bh[192 * 40];
    __shared__ __align__(16) __bf16 Bl[192 * 40];
    __shared__ float smbuf[128][17];
    __shared__ float ssp_s[128];

    const int t = threadIdx.x;
    const int lane = t & 63, wave = t >> 6;
    const int n0 = blockIdx.x * 128;
    const int b = blockIdx.y;
    const int row_base = (wave & 1) * 64;
    const int col_base = (wave >> 1) * 96;
    const int m16 = lane & 15, q = lane >> 4;

    const int an = t & 127;            // A-staging: token
    const int akh = (t >> 7) & 1;      // A-staging: 16-ch half
    const __bf16* ptb = Pt + (size_t)b * (2 * 73728);

    f32x4 acc[4][6];
#pragma unroll
    for (int rt = 0; rt < 4; ++rt)
#pragma unroll
        for (int ct = 0; ct < 6; ++ct)
#pragma unroll
            for (int j = 0; j < 4; ++j) acc[rt][ct][j] = 0.f;
    f32x4 accS[4];
#pragma unroll
    for (int rt = 0; rt < 4; ++rt)
#pragma unroll
        for (int j = 0; j < 4; ++j) accS[rt][j] = 0.f;

    for (int phase = 0; phase < 2; ++phase) {
        if (phase == 1) {
#pragma unroll
            for (int rt = 0; rt < 4; ++rt) {
                int row = row_base + rt * 16 + q * 4;
#pragma unroll
                for (int j = 0; j < 4; ++j)
                    smbuf[row + j][m16] = accS[rt][j];
            }
            __syncthreads();
            if (t < 128) {
                float sp = si_b2[0];
#pragma unroll
                for (int o = 0; o < 12; ++o) {
                    float z = smbuf[t][o] + si_b1[o];
                    float sc = bn3_g[o] / sqrtf(bn3_v[o] + EPSBN);
                    z = z * sc + (bn3_b[o] - bn3_m[o] * sc);
                    sp = fmaf(si_w2[o], gelu_f(z), sp);
                }
                ssp_s[t] = sigmoid_f(sp);
            }
            __syncthreads();
        }
        for (int ki = 0; ki < 6; ++ki) {
            const int kc = (phase == 0) ? (ki + 6) : ki;
            // ---- stage A ----
            {
                const int ch0 = ki * 32 + akh * 16;
                const float* src;
                float scale;
                if (phase == 0) {
                    src = convx + ((size_t)b * Cc + ch0) * Ntok + n0 + an;
                    scale = 1.f;
                } else {
                    src = vbuf + ((size_t)b * Cc + ch0) * Ntok + n0 + an;
                    scale = ssp_s[an];
                }
                float xv[16];
#pragma unroll
                for (int jj = 0; jj < 16; ++jj)
                    xv[jj] = src[(size_t)jj * Ntok] * scale;
                bf16x8 vh0, vl0, vh1, vl1;
                split8(xv, vh0, vl0);
                split8(xv + 8, vh1, vl1);
                const int o = an * 40 + akh * 16;
                *(bf16x8*)&Ah[o] = vh0; *(bf16x8*)&Ah[o + 8] = vh1;
                *(bf16x8*)&Al[o] = vl0; *(bf16x8*)&Al[o + 8] = vl1;
            }
            // ---- stage B from pre-split planes ----
#pragma unroll
            for (int i = 0; i < 3; ++i) {
                int f = i * 256 + t;
                int col = f >> 2, k8 = (f & 3) << 3;
                const __bf16* sp = ptb + (size_t)col * 384 + kc * 32 + k8;
                bf16x8 vh = *(const bf16x8*)sp;
                bf16x8 vl = *(const bf16x8*)(sp + 73728);
                *(bf16x8*)&Bh[col * 40 + k8] = vh;
                *(bf16x8*)&Bl[col * 40 + k8] = vl;
            }
            __syncthreads();

            bf16x8 fah[4], fal[4], fbh[6], fbl[6];
#pragma unroll
            for (int rt = 0; rt < 4; ++rt) {
                int o = (row_base + rt * 16 + m16) * 40 + q * 8;
                fah[rt] = *(const bf16x8*)&Ah[o];
                fal[rt] = *(const bf16x8*)&Al[o];
            }
#pragma unroll
            for (int ct = 0; ct < 6; ++ct) {
                int o = (col_base + ct * 16 + m16) * 40 + q * 8;
                fbh[ct] = *(const bf16x8*)&Bh[o];
            }
#pragma unroll
            for (int rt = 0; rt < 4; ++rt)
#pragma unroll
                for (int ct = 0; ct < 6; ++ct) {
                    acc[rt][ct] = __builtin_amdgcn_mfma_f32_16x16x32_bf16(
                        fah[rt], fbh[ct], acc[rt][ct], 0, 0, 0);
                    acc[rt][ct] = __builtin_amdgcn_mfma_f32_16x16x32_bf16(
                        fal[rt], fbh[ct], acc[rt][ct], 0, 0, 0);
                }
#pragma unroll
            for (int ct = 0; ct < 6; ++ct) {
                int o = (col_base + ct * 16 + m16) * 40 + q * 8;
                fbl[ct] = *(const bf16x8*)&Bl[o];
            }
#pragma unroll
            for (int rt = 0; rt < 4; ++rt)
#pragma unroll
                for (int ct = 0; ct < 6; ++ct)
                    acc[rt][ct] = __builtin_amdgcn_mfma_f32_16x16x32_bf16(
                        fah[rt], fbl[ct], acc[rt][ct], 0, 0, 0);

            if (phase == 0) {
                bf16x8 w1h, w1l;
                if (m16 < 12) {
                    const float* wp = si_w1 + m16 * 192 + ki * 32 + q * 8;
                    float wv[8];
                    float4 u0 = *(const float4*)wp, u1 = *(const float4*)(wp + 4);
                    wv[0] = u0.x; wv[1] = u0.y; wv[2] = u0.z; wv[3] = u0.w;
                    wv[4] = u1.x; wv[5] = u1.y; wv[6] = u1.z; wv[7] = u1.w;
                    split8(wv, w1h, w1l);
                } else {
#pragma unroll
                    for (int j = 0; j < 8; ++j) { w1h[j] = (__bf16)0.f; w1l[j] = (__bf16)0.f; }
                }
#pragma unroll
                for (int rt = 0; rt < 4; ++rt) {
                    accS[rt] = __builtin_amdgcn_mfma_f32_16x16x32_bf16(
                        fah[rt], w1h, accS[rt], 0, 0, 0);
                    accS[rt] = __builtin_amdgcn_mfma_f32_16x16x32_bf16(
                        fal[rt], w1h, accS[rt], 0, 0, 0);
                    accS[rt] = __builtin_amdgcn_mfma_f32_16x16x32_bf16(
                        fah[rt], w1l, accS[rt], 0, 0, 0);
                }
            }
            __syncthreads();
        }
    }

    // ---- epilogue: out (B,N,C) token-major + proj_b ----
    float* ob = out + ((size_t)b * Ntok + n0) * Cc;
#pragma unroll
    for (int ct = 0; ct < 6; ++ct) {
        const int col = col_base + ct * 16 + m16;
        const float pbv = proj_b[col];
#pragma unroll
        for (int rt = 0; rt < 4; ++rt) {
            const int row = row_base + rt * 16 + q * 4;
#pragma unroll
            for (int j = 0; j < 4; ++j)
                ob[(size_t)(row + j) * Cc + col] = acc[rt][ct][j] + pbv;
        }
    }
}

extern "C" void kernel_launch(void* const* d_in, const int* in_sizes, int n_in,
                              void* d_out, int out_size, void* d_ws, size_t ws_size,
                              hipStream_t stream)
{
    const float* x      = (const float*)d_in[0];
    const float* w_qkv  = (const float*)d_in[3];
    const float* temperature = (const float*)d_in[4];
    const float* dw_w   = (const float*)d_in[5];
    const float* dw_b   = (const float*)d_in[6];
    const float* bn1_g  = (const float*)d_in[7];
    const float* bn1_b  = (const float*)d_in[8];
    const float* bn1_m  = (const float*)d_in[9];
    const float* bn1_v  = (const float*)d_in[10];
    const float* ci_w1  = (const float*)d_in[11];
    const float* ci_b1  = (const float*)d_in[12];
    const float* bn2_g  = (const float*)d_in[13];
    const float* bn2_b  = (const float*)d_in[14];
    const float* bn2_m  = (const float*)d_in[15];
    const float* bn2_v  = (const float*)d_in[16];
    const float* ci_w2  = (const float*)d_in[17];
    const float* ci_b2  = (const float*)d_in[18];
    const float* si_w1  = (const float*)d_in[19];
    const float* si_b1  = (const float*)d_in[20];
    const float* bn3_g  = (const float*)d_in[21];
    const float* bn3_b  = (const float*)d_in[22];
    const float* bn3_m  = (const float*)d_in[23];
    const float* bn3_v  = (const float*)d_in[24];
    const float* si_w2  = (const float*)d_in[25];
    const float* si_b2  = (const float*)d_in[26];
    const float* proj_w = (const float*)d_in[27];
    const float* proj_b = (const float*)d_in[28];

    float* ws = (float*)d_ws;
    const size_t BCN = (size_t)Bb * Cc * Ntok;      // 25,165,824
    float* qbuf  = ws;
    float* kbuf  = ws + BCN;
    float* vbuf  = ws + 2 * BCN;
    float* gram  = ws + 3 * BCN;                    // 36864
    float* ssq_q = gram + 36864;                    // 1536
    float* ssq_k = ssq_q + 1536;                    // 1536
    float* vmean = ssq_k + 1536;                    // 1536 (holds channel SUMS)
    float* attn  = vmean + 1536;                    // 36864
    float* sig_ch = attn + 36864;                   // 1536
    float* convx = qbuf;       // q region dead after k_gram -> conv_x
    __bf16* Pt   = (__bf16*)kbuf;  // k region dead after k_gram -> Pbig planes
    float* out = (float*)d_out;

    __bf16* wt = (__bf16*)(out + BCN - 110592);

    hipMemsetAsync(gram, 0, (36864 + 3 * 1536) * sizeof(float), stream);

    k_wprep<<<dim3(432), 256, 0, stream>>>(w_qkv, wt);
    k_qkv_mfma<<<dim3(Ntok / 128, Bb, 3), 256, 0, stream>>>(x, wt, ws, vmean);
    k_gram<<<dim3(Ntok / 512, 2, Bb), 256, 0, stream>>>(qbuf, kbuf, gram, ssq_q, ssq_k);
    k_attn<<<dim3(Bb), 256, 0, stream>>>(gram, ssq_q, ssq_k, temperature, vmean,
                                         ci_w1, ci_b1, bn2_g, bn2_b, bn2_m, bn2_v,
                                         ci_w2, ci_b2, attn, sig_ch);
    k_pprep<<<dim3(Bb, 9), 192, 0, stream>>>(attn, sig_ch, proj_w, Pt);
    k_conv<<<dim3(Him / 8, Cc / 8, Bb), 256, 0, stream>>>(
        vbuf, dw_w, dw_b, bn1_g, bn1_b, bn1_m, bn1_v, convx);
    k_final_mfma<<<dim3(Ntok / 128, Bb), 256, 0, stream>>>(
        vbuf, convx, Pt, si_w1, si_b1, bn3_g, bn3_b, bn3_m, bn3_v,
        si_w2, si_b2, proj_b, out);
}

// Round 2
// 610.309 us; speedup vs baseline: 1.1432x; 1.0222x over previous
//
#include <hip/hip_runtime.h>
#include <math.h>

// Problem constants (fixed by setup_inputs)
#define Bb 8
#define Cc 192
#define NHEADS 8
#define HDim 24
#define Him 128
#define Wim 128
#define Ntok 16384   // H*W
#define EPSBN 1e-5f

typedef __bf16 bf16x8 __attribute__((ext_vector_type(8)));
typedef float  f32x4  __attribute__((ext_vector_type(4)));

static __device__ __forceinline__ float gelu_f(float v) {
    return 0.5f * v * (1.0f + erff(v * 0.70710678118654752f));
}
static __device__ __forceinline__ float sigmoid_f(float v) {
    return 1.0f / (1.0f + expf(-v));
}
static __device__ __forceinline__ void split8(const float* xv, bf16x8& h8, bf16x8& l8) {
#pragma unroll
    for (int j = 0; j < 8; ++j) {
        float v = xv[j];
        __bf16 h = (__bf16)v;
        h8[j] = h;
        l8[j] = (__bf16)(v - (float)h);
    }
}

// ---------------------------------------------------------------------------
// K0: one-time prep: transpose v-part of w_qkv (192x192 fp32, cols 384..575)
// into bf16 hi/lo planes in [col][k] layout. Stored in tail of d_out (dead
// until k_final's final write).
// ---------------------------------------------------------------------------
__global__ __launch_bounds__(256) void k_wprep(const float* __restrict__ w,
                                               __bf16* __restrict__ wt)
{
    int idx = blockIdx.x * 256 + threadIdx.x;   // 192*192 = 36864 total
    if (idx >= 36864) return;
    int k = idx / 192, c = idx % 192;           // coalesced read over c
    float v = w[k * 576 + 384 + c];
    __bf16 h = (__bf16)v;
    __bf16 l = (__bf16)(v - (float)h);
    wt[c * 192 + k] = h;
    wt[36864 + c * 192 + k] = l;
}

// ---------------------------------------------------------------------------
// K_xtx: per-batch input Gram partials. XtX = x^T x over tokens, computed per
// 256-token chunk with split-bf16 MFMA, fragments gathered straight from
// global (verified 16x16x32 layouts: A/B lane = ch (l&15), k = (l>>4)*8+j;
// C: col = l&15, row = (l>>4)*4+j). Block = 256 thr, 4 waves in quadrants of
// the 192x192 output (each wave 96x96 = 6x6 16-tiles). Partials to xpart.
// ---------------------------------------------------------------------------
__global__ __launch_bounds__(256, 2) void k_xtx(const float* __restrict__ x,
                                                float* __restrict__ xpart)
{
    const int t = threadIdx.x;
    const int lane = t & 63, wave = t >> 6;
    const int chunk = blockIdx.x;      // 64 chunks of 256 tokens
    const int b = blockIdx.y;
    const int n0 = chunk * 256;
    const int m16 = lane & 15, q = lane >> 4;
    const int rq = (wave & 1) * 6;     // row 16-ch-group base
    const int cq = (wave >> 1) * 6;    // col 16-ch-group base

    f32x4 acc[6][6];
#pragma unroll
    for (int i = 0; i < 6; ++i)
#pragma unroll
        for (int j = 0; j < 6; ++j)
#pragma unroll
            for (int r = 0; r < 4; ++r) acc[i][j][r] = 0.f;

    const float* xb = x + ((size_t)b * Ntok + n0) * 192;

    for (int kt = 0; kt < 8; ++kt) {
        const float* base = xb + (size_t)(kt * 32 + q * 8) * 192 + m16;
#pragma unroll
        for (int rb = 0; rb < 2; ++rb) {
            bf16x8 fah[3], fal[3];
#pragma unroll
            for (int g = 0; g < 3; ++g) {
                const float* src = base + (rq + rb * 3 + g) * 16;
                float xv[8];
#pragma unroll
                for (int j = 0; j < 8; ++j) xv[j] = src[(size_t)j * 192];
                split8(xv, fah[g], fal[g]);
            }
#pragma unroll
            for (int cb = 0; cb < 2; ++cb) {
                bf16x8 fbh[3], fbl[3];
#pragma unroll
                for (int g = 0; g < 3; ++g) {
                    const float* src = base + (cq + cb * 3 + g) * 16;
                    float xv[8];
#pragma unroll
                    for (int j = 0; j < 8; ++j) xv[j] = src[(size_t)j * 192];
                    split8(xv, fbh[g], fbl[g]);
                }
#pragma unroll
                for (int ti = 0; ti < 3; ++ti)
#pragma unroll
                    for (int tj = 0; tj < 3; ++tj) {
                        f32x4& a = acc[rb * 3 + ti][cb * 3 + tj];
                        a = __builtin_amdgcn_mfma_f32_16x16x32_bf16(fah[ti], fbh[tj], a, 0, 0, 0);
                        a = __builtin_amdgcn_mfma_f32_16x16x32_bf16(fah[ti], fbl[tj], a, 0, 0, 0);
                        a = __builtin_amdgcn_mfma_f32_16x16x32_bf16(fal[ti], fbh[tj], a, 0, 0, 0);
                    }
            }
        }
    }
    float* op = xpart + ((size_t)b * 64 + chunk) * 36864;
#pragma unroll
    for (int ti = 0; ti < 6; ++ti)
#pragma unroll
        for (int tj = 0; tj < 6; ++tj) {
            const int row0 = (rq + ti) * 16 + q * 4;
            const int col = (cq + tj) * 16 + m16;
#pragma unroll
            for (int j = 0; j < 4; ++j)
                op[(size_t)(row0 + j) * 192 + col] = acc[ti][tj][j];
        }
}

// ---------------------------------------------------------------------------
// K_xred: reduce 64 chunk-partials -> XtX[b] (192x192 per batch).
// ---------------------------------------------------------------------------
__global__ __launch_bounds__(256) void k_xred(const float* __restrict__ xpart,
                                              float* __restrict__ XtX)
{
    const int b = blockIdx.y;
    const int e = blockIdx.x * 256 + threadIdx.x;   // 36864 = 144*256
    const float* p = xpart + (size_t)b * 64 * 36864 + e;
    float s = 0.f;
#pragma unroll
    for (int c = 0; c < 64; ++c) s += p[(size_t)c * 36864];
    XtX[(size_t)b * 36864 + e] = s;
}

// ---------------------------------------------------------------------------
// K_gram2: gram[b,h] = Wq_h^T XtX_b Wk_h; ssq_q[c] = Wq_c^T XtX Wq_c;
// ssq_k likewise. All fp32. Grid (B, HEADS).
// ---------------------------------------------------------------------------
__global__ __launch_bounds__(256) void k_gram2(const float* __restrict__ XtX,
                                               const float* __restrict__ w_qkv,
                                               float* __restrict__ gram,
                                               float* __restrict__ ssq_q,
                                               float* __restrict__ ssq_k)
{
    __shared__ float wq[192][24];
    __shared__ float wk[192][24];
    __shared__ float U[192][24];
    __shared__ float V[192][24];
    const int b = blockIdx.x, h = blockIdx.y, t = threadIdx.x;
    for (int e = t; e < 4608; e += 256) {
        int k = e / 24, c = e % 24;
        wq[k][c] = w_qkv[k * 576 + h * 24 + c];
        wk[k][c] = w_qkv[k * 576 + 192 + h * 24 + c];
    }
    __syncthreads();
    if (t < 192) {
        const float* xr = XtX + (size_t)b * 36864 + (size_t)t * 192;
        float u[24], v[24];
#pragma unroll
        for (int c = 0; c < 24; ++c) { u[c] = 0.f; v[c] = 0.f; }
        for (int k4 = 0; k4 < 48; ++k4) {
            float4 x4 = *(const float4*)(xr + k4 * 4);
#pragma unroll
            for (int kk = 0; kk < 4; ++kk) {
                float xv = (&x4.x)[kk];
                int k = k4 * 4 + kk;
#pragma unroll
                for (int c = 0; c < 24; ++c) {
                    u[c] = fmaf(xv, wq[k][c], u[c]);
                    v[c] = fmaf(xv, wk[k][c], v[c]);
                }
            }
        }
#pragma unroll
        for (int c = 0; c < 24; ++c) { U[t][c] = u[c]; V[t][c] = v[c]; }
    }
    __syncthreads();
    for (int o = t; o < 576; o += 256) {
        int c = o / 24, d = o % 24;
        float g = 0.f;
        for (int r = 0; r < 192; ++r) g = fmaf(wq[r][c], V[r][d], g);
        gram[(size_t)(b * NHEADS + h) * 576 + o] = g;
    }
    if (t < 24) {
        float s = 0.f;
        for (int r = 0; r < 192; ++r) s = fmaf(wq[r][t], U[r][t], s);
        ssq_q[b * Cc + h * HDim + t] = s;
    } else if (t < 48) {
        int c = t - 24;
        float s = 0.f;
        for (int r = 0; r < 192; ++r) s = fmaf(wk[r][c], V[r][c], s);
        ssq_k[b * Cc + h * HDim + c] = s;
    }
}

// ---------------------------------------------------------------------------
// K1 (v-only now): v projection via split-bf16 MFMA. Block = 128 tokens x
// 192 v-cols. Output transposed to (B,C,N). Also accumulates per-channel
// v sums for the channel gate.
// ---------------------------------------------------------------------------
__global__ __launch_bounds__(256, 2) void k_qkv_mfma(const float* __restrict__ x,
                                                     const __bf16* __restrict__ wt,
                                                     float* __restrict__ vout,
                                                     float* __restrict__ vsum)
{
    __shared__ __align__(16) __bf16 Ah[128 * 40];
    __shared__ __align__(16) __bf16 Al[128 * 40];
    __shared__ __align__(16) __bf16 Bh[192 * 40];
    __shared__ __align__(16) __bf16 Bl[192 * 40];

    const int t = threadIdx.x;
    const int lane = t & 63, wave = t >> 6;
    const int n0 = blockIdx.x * 128;
    const int b = blockIdx.y;
    const int row_base = (wave & 1) * 64;
    const int col_base = (wave >> 1) * 96;
    const int m16 = lane & 15, q = lane >> 4;

    f32x4 acc[4][6];
#pragma unroll
    for (int rt = 0; rt < 4; ++rt)
#pragma unroll
        for (int ct = 0; ct < 6; ++ct)
#pragma unroll
            for (int j = 0; j < 4; ++j) acc[rt][ct][j] = 0.f;

    const int ar = t >> 1, ahalf = t & 1;
    const float* xrow = x + ((size_t)b * Ntok + n0 + ar) * Cc + ahalf * 16;

    for (int kc = 0; kc < 6; ++kc) {
        {
            const float4* xp4 = (const float4*)(xrow + kc * 32);
            float xv[16];
            float4 u;
            u = xp4[0]; xv[0] = u.x; xv[1] = u.y; xv[2]  = u.z; xv[3]  = u.w;
            u = xp4[1]; xv[4] = u.x; xv[5] = u.y; xv[6]  = u.z; xv[7]  = u.w;
            u = xp4[2]; xv[8] = u.x; xv[9] = u.y; xv[10] = u.z; xv[11] = u.w;
            u = xp4[3]; xv[12] = u.x; xv[13] = u.y; xv[14] = u.z; xv[15] = u.w;
            bf16x8 vh0, vh1, vl0, vl1;
            split8(xv, vh0, vl0);
            split8(xv + 8, vh1, vl1);
            const int o = ar * 40 + ahalf * 16;
            *(bf16x8*)&Ah[o] = vh0; *(bf16x8*)&Ah[o + 8] = vh1;
            *(bf16x8*)&Al[o] = vl0; *(bf16x8*)&Al[o + 8] = vl1;
        }
#pragma unroll
        for (int i = 0; i < 3; ++i) {
            int f = i * 256 + t;
            int n = f >> 2, k8 = (f & 3) << 3;
            const __bf16* src = wt + (size_t)n * 192 + kc * 32 + k8;
            bf16x8 vh = *(const bf16x8*)src;
            bf16x8 vl = *(const bf16x8*)(src + 36864);
            *(bf16x8*)&Bh[n * 40 + k8] = vh;
            *(bf16x8*)&Bl[n * 40 + k8] = vl;
        }
        __syncthreads();

        bf16x8 fah[4], fal[4], fbh[6], fbl[6];
#pragma unroll
        for (int rt = 0; rt < 4; ++rt) {
            int o = (row_base + rt * 16 + m16) * 40 + q * 8;
            fah[rt] = *(const bf16x8*)&Ah[o];
            fal[rt] = *(const bf16x8*)&Al[o];
        }
#pragma unroll
        for (int ct = 0; ct < 6; ++ct) {
            int o = (col_base + ct * 16 + m16) * 40 + q * 8;
            fbh[ct] = *(const bf16x8*)&Bh[o];
            fbl[ct] = *(const bf16x8*)&Bl[o];
        }
#pragma unroll
        for (int rt = 0; rt < 4; ++rt)
#pragma unroll
            for (int ct = 0; ct < 6; ++ct) {
                acc[rt][ct] = __builtin_amdgcn_mfma_f32_16x16x32_bf16(
                    fah[rt], fbh[ct], acc[rt][ct], 0, 0, 0);
                acc[rt][ct] = __builtin_amdgcn_mfma_f32_16x16x32_bf16(
                    fah[rt], fbl[ct], acc[rt][ct], 0, 0, 0);
                acc[rt][ct] = __builtin_amdgcn_mfma_f32_16x16x32_bf16(
                    fal[rt], fbh[ct], acc[rt][ct], 0, 0, 0);
            }
        __syncthreads();
    }

    const size_t obase = (size_t)b * Cc * (size_t)Ntok;
#pragma unroll
    for (int rt = 0; rt < 4; ++rt)
#pragma unroll
        for (int ct = 0; ct < 6; ++ct) {
            int token = n0 + row_base + rt * 16 + q * 4;
            int col = col_base + ct * 16 + m16;
            float4 o = make_float4(acc[rt][ct][0], acc[rt][ct][1],
                                   acc[rt][ct][2], acc[rt][ct][3]);
            *(float4*)(vout + obase + (size_t)col * Ntok + token) = o;
        }

#pragma unroll
    for (int ct = 0; ct < 6; ++ct) {
        float s = 0.f;
#pragma unroll
        for (int rt = 0; rt < 4; ++rt)
            s += acc[rt][ct][0] + acc[rt][ct][1] + acc[rt][ct][2] + acc[rt][ct][3];
        s += __shfl_xor(s, 16, 64);
        s += __shfl_xor(s, 32, 64);
        if (q == 0)
            atomicAdd(vsum + b * Cc + col_base + ct * 16 + m16, s);
    }
}

// K4: normalize gram -> softmax attn; pooled = attn @ vmean; channel-gate MLP.
__global__ __launch_bounds__(256) void k_attn(const float* __restrict__ gram,
                                              const float* __restrict__ ssq_q,
                                              const float* __restrict__ ssq_k,
                                              const float* __restrict__ temperature,
                                              const float* __restrict__ vmean,
                                              const float* __restrict__ ci_w1,
                                              const float* __restrict__ ci_b1,
                                              const float* __restrict__ bn2_g,
                                              const float* __restrict__ bn2_b,
                                              const float* __restrict__ bn2_m,
                                              const float* __restrict__ bn2_v,
                                              const float* __restrict__ ci_w2,
                                              const float* __restrict__ ci_b2,
                                              float* __restrict__ attn,
                                              float* __restrict__ sig_ch)
{
    __shared__ float pooled[192];
    __shared__ float cmv[24];
    const int b = blockIdx.x, t = threadIdx.x;
    if (t < 192) {
        int h = t / 24, c = t % 24;
        const float* gp = gram + (size_t)(b * NHEADS + h) * 576 + c * 24;
        float qn = fmaxf(sqrtf(ssq_q[b * Cc + h * HDim + c]), 1e-12f);
        float temp = temperature[h];
        float logit[24];
        float m = -1e30f;
#pragma unroll
        for (int d = 0; d < 24; ++d) {
            float kn = fmaxf(sqrtf(ssq_k[b * Cc + h * HDim + d]), 1e-12f);
            float l = gp[d] / (qn * kn) * temp;
            logit[d] = l; m = fmaxf(m, l);
        }
        float s = 0.f;
#pragma unroll
        for (int d = 0; d < 24; ++d) { float e = expf(logit[d] - m); logit[d] = e; s += e; }
        float inv = 1.f / s;
        float pool = 0.f;
        float* ap = attn + (size_t)(b * NHEADS + h) * 576 + c * 24;
#pragma unroll
        for (int d = 0; d < 24; ++d) {
            float a = logit[d] * inv;
            ap[d] = a;
            pool = fmaf(a, vmean[b * Cc + h * HDim + d], pool);
        }
        pooled[h * 24 + c] = pool * (1.0f / (float)Ntok);
    }
    __syncthreads();
    if (t < 24) {
        float z = ci_b1[t];
        for (int c = 0; c < 192; ++c) z = fmaf(ci_w1[t * 192 + c], pooled[c], z);
        float sc = bn2_g[t] / sqrtf(bn2_v[t] + EPSBN);
        z = z * sc + (bn2_b[t] - bn2_m[t] * sc);
        cmv[t] = gelu_f(z);
    }
    __syncthreads();
    if (t < 192) {
        float z = ci_b2[t];
#pragma unroll
        for (int o = 0; o < 24; ++o) z = fmaf(ci_w2[t * 24 + o], cmv[o], z);
        sig_ch[b * Cc + t] = sigmoid_f(z);
    }
}

// ---------------------------------------------------------------------------
// K4b: fold attention + channel gate into projection.
// ---------------------------------------------------------------------------
__global__ __launch_bounds__(192) void k_pprep(const float* __restrict__ attn,
                                               const float* __restrict__ sig_ch,
                                               const float* __restrict__ proj_w,
                                               __bf16* __restrict__ Pt)
{
    const int b = blockIdx.x, part = blockIdx.y, j = threadIdx.x;
    __bf16* base = Pt + (size_t)b * (2 * 73728);   // 73728 = 192*384
    if (part < 8) {
        const int h = part;
        __shared__ float at[576];
        for (int e = j; e < 576; e += 192) at[e] = attn[(size_t)(b * 8 + h) * 576 + e];
        __syncthreads();
        float pr[24];
#pragma unroll
        for (int cl = 0; cl < 24; ++cl) pr[cl] = proj_w[(h * 24 + cl) * 192 + j];
        float s[24];
#pragma unroll
        for (int d = 0; d < 24; ++d) s[d] = 0.f;
#pragma unroll
        for (int cl = 0; cl < 24; ++cl) {
            float a = pr[cl];
#pragma unroll
            for (int d = 0; d < 24; ++d) s[d] = fmaf(a, at[cl * 24 + d], s[d]);
        }
#pragma unroll
        for (int d = 0; d < 24; ++d) {
            float v = s[d];
            __bf16 hi = (__bf16)v;
            base[j * 384 + h * 24 + d] = hi;
            base[73728 + j * 384 + h * 24 + d] = (__bf16)(v - (float)hi);
        }
    } else {
        __shared__ float sch_s[192];
        sch_s[j] = sig_ch[b * Cc + j];
        __syncthreads();
        for (int ch = 0; ch < 192; ++ch) {
            float v = sch_s[ch] * proj_w[ch * 192 + j];
            __bf16 hi = (__bf16)v;
            base[j * 384 + 192 + ch] = hi;
            base[73728 + j * 384 + 192 + ch] = (__bf16)(v - (float)hi);
        }
    }
}

// ---------------------------------------------------------------------------
// K5: depthwise 3x3 conv + BN1 + GELU. Block = 8 rows x 128 px x 8 ch;
// grid (16, 24, B) = 3072 blocks.
// ---------------------------------------------------------------------------
__global__ __launch_bounds__(256) void k_conv(const float* __restrict__ vbuf,
                                              const float* __restrict__ dw_w,
                                              const float* __restrict__ dw_b,
                                              const float* __restrict__ bn1_g,
                                              const float* __restrict__ bn1_b,
                                              const float* __restrict__ bn1_m,
                                              const float* __restrict__ bn1_v,
                                              float* __restrict__ convx)
{
    __shared__ float vh[8][10][130];   // 8 ch x 10 rows x (1 | 128 | 1) pad cols
    __shared__ float dww[8 * 9];
    __shared__ float scl[8], shf[8];
    const int t = threadIdx.x;
    const int y0 = blockIdx.x * 8;
    const int ch0 = blockIdx.y * 8;
    const int b = blockIdx.z;

    if (t < 72) {
        dww[t] = dw_w[ch0 * 9 + t];
    } else if (t < 80) {
        int c = t - 72, ch = ch0 + c;
        float sc = bn1_g[ch] / sqrtf(bn1_v[ch] + EPSBN);
        scl[c] = sc;
        shf[c] = (dw_b[ch] - bn1_m[ch]) * sc + bn1_b[ch];
    } else if (t < 160) {
        int e = t - 80;                 // zero the x-pad columns
        int ch = e / 10, r = e % 10;
        vh[ch][r][0] = 0.f;
        vh[ch][r][129] = 0.f;
    }
    // stage 8ch x 10 rows x 128 cols (rows y0-1 .. y0+8), coalesced full rows
    for (int e = t; e < 8 * 10 * 128; e += 256) {
        int ch = e / 1280, rem = e - ch * 1280;
        int r = rem >> 7, xc = rem & 127;
        int gy = y0 - 1 + r;
        float v = 0.f;
        if (gy >= 0 && gy < Him)
            v = vbuf[((size_t)b * Cc + ch0 + ch) * Ntok + gy * Wim + xc];
        vh[ch][r][xc + 1] = v;
    }
    __syncthreads();

    const int xc = t & 127, half = t >> 7;   // half: rows 0-3 / 4-7
#pragma unroll
    for (int ch = 0; ch < 8; ++ch) {
        const float w0 = dww[ch * 9 + 0], w1 = dww[ch * 9 + 1], w2 = dww[ch * 9 + 2];
        const float w3 = dww[ch * 9 + 3], w4 = dww[ch * 9 + 4], w5 = dww[ch * 9 + 5];
        const float w6 = dww[ch * 9 + 6], w7 = dww[ch * 9 + 7], w8 = dww[ch * 9 + 8];
        const float sc = scl[ch], sh = shf[ch];
        float* op = convx + ((size_t)b * Cc + ch0 + ch) * Ntok + (size_t)y0 * Wim + xc;
#pragma unroll
        for (int rr = 0; rr < 4; ++rr) {
            int r = half * 4 + rr;               // output row within tile
            const float* r0 = &vh[ch][r][xc];    // source rows r, r+1, r+2
            const float* r1 = &vh[ch][r + 1][xc];
            const float* r2 = &vh[ch][r + 2][xc];
            float conv = r0[0] * w0 + r0[1] * w1 + r0[2] * w2
                       + r1[0] * w3 + r1[1] * w4 + r1[2] * w5
                       + r2[0] * w6 + r2[1] * w7 + r2[2] * w8;
            op[(size_t)r * Wim] = gelu_f(conv * sc + sh);
        }
    }
}

// ---------------------------------------------------------------------------
// K6: fused epilogue GEMM + spatial-gate MLP.
// Phase 0 (kc 6..11): A = convx chunks; MFMA vs P_conv AND vs si_w1^T.
// Gate: dump to padded LDS, 128 threads do BN3+GELU+w2+sigmoid -> ssp_s.
// Phase 1 (kc 0..5): A = v chunks scaled by ssp_s[token]; MFMA vs P_att.
// ---------------------------------------------------------------------------
__global__ __launch_bounds__(256, 2) void k_final_mfma(const float* __restrict__ vbuf,
                                                       const float* __restrict__ convx,
                                                       const __bf16* __restrict__ Pt,
                                                       const float* __restrict__ si_w1,
                                                       const float* __restrict__ si_b1,
                                                       const float* __restrict__ bn3_g,
                                                       const float* __restrict__ bn3_b,
                                                       const float* __restrict__ bn3_m,
                                                       const float* __restrict__ bn3_v,
                                                       const float* __restrict__ si_w2,
                                                       const float* __restrict__ si_b2,
                                                       const float* __restrict__ proj_b,
                                                       float* __restrict__ out)
{
    __shared__ __align__(16) __bf16 Ah[128 * 40];
    __shared__ __align__(16) __bf16 Al[128 * 40];
    __shared__ __align__(16) __bf16 Bh[192 * 40];
    __shared__ __align__(16) __bf16 Bl[192 * 40];
    __shared__ float smbuf[128][17];
    __shared__ float ssp_s[128];

    const int t = threadIdx.x;
    const int lane = t & 63, wave = t >> 6;
    const int n0 = blockIdx.x * 128;
    const int b = blockIdx.y;
    const int row_base = (wave & 1) * 64;
    const int col_base = (wave >> 1) * 96;
    const int m16 = lane & 15, q = lane >> 4;

    const int an = t & 127;            // A-staging: token
    const int akh = (t >> 7) & 1;      // A-staging: 16-ch half
    const __bf16* ptb = Pt + (size_t)b * (2 * 73728);

    f32x4 acc[4][6];
#pragma unroll
    for (int rt = 0; rt < 4; ++rt)
#pragma unroll
        for (int ct = 0; ct < 6; ++ct)
#pragma unroll
            for (int j = 0; j < 4; ++j) acc[rt][ct][j] = 0.f;
    f32x4 accS[4];
#pragma unroll
    for (int rt = 0; rt < 4; ++rt)
#pragma unroll
        for (int j = 0; j < 4; ++j) accS[rt][j] = 0.f;

    for (int phase = 0; phase < 2; ++phase) {
        if (phase == 1) {
#pragma unroll
            for (int rt = 0; rt < 4; ++rt) {
                int row = row_base + rt * 16 + q * 4;
#pragma unroll
                for (int j = 0; j < 4; ++j)
                    smbuf[row + j][m16] = accS[rt][j];
            }
            __syncthreads();
            if (t < 128) {
                float sp = si_b2[0];
#pragma unroll
                for (int o = 0; o < 12; ++o) {
                    float z = smbuf[t][o] + si_b1[o];
                    float sc = bn3_g[o] / sqrtf(bn3_v[o] + EPSBN);
                    z = z * sc + (bn3_b[o] - bn3_m[o] * sc);
                    sp = fmaf(si_w2[o], gelu_f(z), sp);
                }
                ssp_s[t] = sigmoid_f(sp);
            }
            __syncthreads();
        }
        for (int ki = 0; ki < 6; ++ki) {
            const int kc = (phase == 0) ? (ki + 6) : ki;
            // ---- stage A ----
            {
                const int ch0 = ki * 32 + akh * 16;
                const float* src;
                float scale;
                if (phase == 0) {
                    src = convx + ((size_t)b * Cc + ch0) * Ntok + n0 + an;
                    scale = 1.f;
                } else {
                    src = vbuf + ((size_t)b * Cc + ch0) * Ntok + n0 + an;
                    scale = ssp_s[an];
                }
                float xv[16];
#pragma unroll
                for (int jj = 0; jj < 16; ++jj)
                    xv[jj] = src[(size_t)jj * Ntok] * scale;
                bf16x8 vh0, vl0, vh1, vl1;
                split8(xv, vh0, vl0);
                split8(xv + 8, vh1, vl1);
                const int o = an * 40 + akh * 16;
                *(bf16x8*)&Ah[o] = vh0; *(bf16x8*)&Ah[o + 8] = vh1;
                *(bf16x8*)&Al[o] = vl0; *(bf16x8*)&Al[o + 8] = vl1;
            }
            // ---- stage B from pre-split planes ----
#pragma unroll
            for (int i = 0; i < 3; ++i) {
                int f = i * 256 + t;
                int col = f >> 2, k8 = (f & 3) << 3;
                const __bf16* sp = ptb + (size_t)col * 384 + kc * 32 + k8;
                bf16x8 vh = *(const bf16x8*)sp;
                bf16x8 vl = *(const bf16x8*)(sp + 73728);
                *(bf16x8*)&Bh[col * 40 + k8] = vh;
                *(bf16x8*)&Bl[col * 40 + k8] = vl;
            }
            __syncthreads();

            bf16x8 fah[4], fal[4], fbh[6], fbl[6];
#pragma unroll
            for (int rt = 0; rt < 4; ++rt) {
                int o = (row_base + rt * 16 + m16) * 40 + q * 8;
                fah[rt] = *(const bf16x8*)&Ah[o];
                fal[rt] = *(const bf16x8*)&Al[o];
            }
#pragma unroll
            for (int ct = 0; ct < 6; ++ct) {
                int o = (col_base + ct * 16 + m16) * 40 + q * 8;
                fbh[ct] = *(const bf16x8*)&Bh[o];
            }
#pragma unroll
            for (int rt = 0; rt < 4; ++rt)
#pragma unroll
                for (int ct = 0; ct < 6; ++ct) {
                    acc[rt][ct] = __builtin_amdgcn_mfma_f32_16x16x32_bf16(
                        fah[rt], fbh[ct], acc[rt][ct], 0, 0, 0);
                    acc[rt][ct] = __builtin_amdgcn_mfma_f32_16x16x32_bf16(
                        fal[rt], fbh[ct], acc[rt][ct], 0, 0, 0);
                }
#pragma unroll
            for (int ct = 0; ct < 6; ++ct) {
                int o = (col_base + ct * 16 + m16) * 40 + q * 8;
                fbl[ct] = *(const bf16x8*)&Bl[o];
            }
#pragma unroll
            for (int rt = 0; rt < 4; ++rt)
#pragma unroll
                for (int ct = 0; ct < 6; ++ct)
                    acc[rt][ct] = __builtin_amdgcn_mfma_f32_16x16x32_bf16(
                        fah[rt], fbl[ct], acc[rt][ct], 0, 0, 0);

            if (phase == 0) {
                bf16x8 w1h, w1l;
                if (m16 < 12) {
                    const float* wp = si_w1 + m16 * 192 + ki * 32 + q * 8;
                    float wv[8];
                    float4 u0 = *(const float4*)wp, u1 = *(const float4*)(wp + 4);
                    wv[0] = u0.x; wv[1] = u0.y; wv[2] = u0.z; wv[3] = u0.w;
                    wv[4] = u1.x; wv[5] = u1.y; wv[6] = u1.z; wv[7] = u1.w;
                    split8(wv, w1h, w1l);
                } else {
#pragma unroll
                    for (int j = 0; j < 8; ++j) { w1h[j] = (__bf16)0.f; w1l[j] = (__bf16)0.f; }
                }
#pragma unroll
                for (int rt = 0; rt < 4; ++rt) {
                    accS[rt] = __builtin_amdgcn_mfma_f32_16x16x32_bf16(
                        fah[rt], w1h, accS[rt], 0, 0, 0);
                    accS[rt] = __builtin_amdgcn_mfma_f32_16x16x32_bf16(
                        fal[rt], w1h, accS[rt], 0, 0, 0);
                    accS[rt] = __builtin_amdgcn_mfma_f32_16x16x32_bf16(
                        fah[rt], w1l, accS[rt], 0, 0, 0);
                }
            }
            __syncthreads();
        }
    }

    // ---- epilogue: out (B,N,C) token-major + proj_b ----
    float* ob = out + ((size_t)b * Ntok + n0) * Cc;
#pragma unroll
    for (int ct = 0; ct < 6; ++ct) {
        const int col = col_base + ct * 16 + m16;
        const float pbv = proj_b[col];
#pragma unroll
        for (int rt = 0; rt < 4; ++rt) {
            const int row = row_base + rt * 16 + q * 4;
#pragma unroll
            for (int j = 0; j < 4; ++j)
                ob[(size_t)(row + j) * Cc + col] = acc[rt][ct][j] + pbv;
        }
    }
}

extern "C" void kernel_launch(void* const* d_in, const int* in_sizes, int n_in,
                              void* d_out, int out_size, void* d_ws, size_t ws_size,
                              hipStream_t stream)
{
    const float* x      = (const float*)d_in[0];
    const float* w_qkv  = (const float*)d_in[3];
    const float* temperature = (const float*)d_in[4];
    const float* dw_w   = (const float*)d_in[5];
    const float* dw_b   = (const float*)d_in[6];
    const float* bn1_g  = (const float*)d_in[7];
    const float* bn1_b  = (const float*)d_in[8];
    const float* bn1_m  = (const float*)d_in[9];
    const float* bn1_v  = (const float*)d_in[10];
    const float* ci_w1  = (const float*)d_in[11];
    const float* ci_b1  = (const float*)d_in[12];
    const float* bn2_g  = (const float*)d_in[13];
    const float* bn2_b  = (const float*)d_in[14];
    const float* bn2_m  = (const float*)d_in[15];
    const float* bn2_v  = (const float*)d_in[16];
    const float* ci_w2  = (const float*)d_in[17];
    const float* ci_b2  = (const float*)d_in[18];
    const float* si_w1  = (const float*)d_in[19];
    const float* si_b1  = (const float*)d_in[20];
    const float* bn3_g  = (const float*)d_in[21];
    const float* bn3_b  = (const float*)d_in[22];
    const float* bn3_m  = (const float*)d_in[23];
    const float* bn3_v  = (const float*)d_in[24];
    const float* si_w2  = (const float*)d_in[25];
    const float* si_b2  = (const float*)d_in[26];
    const float* proj_w = (const float*)d_in[27];
    const float* proj_b = (const float*)d_in[28];

    float* ws = (float*)d_ws;
    const size_t BCN = (size_t)Bb * Cc * Ntok;      // 25,165,824
    float* vbuf  = ws;
    float* convx = ws + BCN;
    __bf16* Pt   = (__bf16*)(ws + 2 * BCN);         // 8*2*73728 bf16 = 589824 f
    float* xpart = ws + 2 * BCN + 589824;           // 512*36864 = 18,874,368
    float* XtX   = xpart + 18874368;                // 294,912
    float* gram  = XtX + 294912;                    // 36864
    float* ssq_q = gram + 36864;                    // 1536
    float* ssq_k = ssq_q + 1536;                    // 1536
    float* vmean = ssq_k + 1536;                    // 1536 (holds channel SUMS)
    float* attn  = vmean + 1536;                    // 36864
    float* sig_ch = attn + 36864;                   // 1536
    float* out = (float*)d_out;

    __bf16* wt = (__bf16*)(out + BCN - 36864);      // 73728 bf16 in out tail

    hipMemsetAsync(vmean, 0, 1536 * sizeof(float), stream);

    k_wprep<<<dim3(144), 256, 0, stream>>>(w_qkv, wt);
    k_xtx<<<dim3(64, Bb), 256, 0, stream>>>(x, xpart);
    k_xred<<<dim3(144, Bb), 256, 0, stream>>>(xpart, XtX);
    k_gram2<<<dim3(Bb, NHEADS), 256, 0, stream>>>(XtX, w_qkv, gram, ssq_q, ssq_k);
    k_qkv_mfma<<<dim3(Ntok / 128, Bb), 256, 0, stream>>>(x, wt, vbuf, vmean);
    k_attn<<<dim3(Bb), 256, 0, stream>>>(gram, ssq_q, ssq_k, temperature, vmean,
                                         ci_w1, ci_b1, bn2_g, bn2_b, bn2_m, bn2_v,
                                         ci_w2, ci_b2, attn, sig_ch);
    k_pprep<<<dim3(Bb, 9), 192, 0, stream>>>(attn, sig_ch, proj_w, Pt);
    k_conv<<<dim3(Him / 8, Cc / 8, Bb), 256, 0, stream>>>(
        vbuf, dw_w, dw_b, bn1_g, bn1_b, bn1_m, bn1_v, convx);
    k_final_mfma<<<dim3(Ntok / 128, Bb), 256, 0, stream>>>(
        vbuf, convx, Pt, si_w1, si_b1, bn3_g, bn3_b, bn3_m, bn3_v,
        si_w2, si_b2, proj_b, out);
}

// Round 3
// 559.595 us; speedup vs baseline: 1.2468x; 1.0906x over previous
//
#include <hip/hip_runtime.h>
#include <math.h>

// Problem constants (fixed by setup_inputs)
#define Bb 8
#define Cc 192
#define NHEADS 8
#define HDim 24
#define Him 128
#define Wim 128
#define Ntok 16384   // H*W
#define EPSBN 1e-5f

typedef __bf16 bf16x8 __attribute__((ext_vector_type(8)));
typedef __bf16 bf16x2 __attribute__((ext_vector_type(2)));
typedef float  f32x4  __attribute__((ext_vector_type(4)));

static __device__ __forceinline__ float gelu_f(float v) {
    return 0.5f * v * (1.0f + erff(v * 0.70710678118654752f));
}
static __device__ __forceinline__ float sigmoid_f(float v) {
    return 1.0f / (1.0f + expf(-v));
}
static __device__ __forceinline__ void split8(const float* xv, bf16x8& h8, bf16x8& l8) {
#pragma unroll
    for (int j = 0; j < 8; ++j) {
        float v = xv[j];
        __bf16 h = (__bf16)v;
        h8[j] = h;
        l8[j] = (__bf16)(v - (float)h);
    }
}

// ---------------------------------------------------------------------------
// K0: one-time prep: transpose v-part of w_qkv (192x192 fp32, cols 384..575)
// into bf16 hi/lo planes in [col][k] layout. Stored in tail of d_out.
// ---------------------------------------------------------------------------
__global__ __launch_bounds__(256) void k_wprep(const float* __restrict__ w,
                                               __bf16* __restrict__ wt)
{
    int idx = blockIdx.x * 256 + threadIdx.x;   // 192*192 = 36864 total
    if (idx >= 36864) return;
    int k = idx / 192, c = idx % 192;           // coalesced read over c
    float v = w[k * 576 + 384 + c];
    __bf16 h = (__bf16)v;
    __bf16 l = (__bf16)(v - (float)h);
    wt[c * 192 + k] = h;
    wt[36864 + c * 192 + k] = l;
}

// ---------------------------------------------------------------------------
// K_xtx v2: per-batch input Gram partials via LDS-transposed staging.
// Chunk = 512 tokens (grid 32 x B). Per 32-token k-step: stage x^T into LDS
// as [192 ch][32 tok] bf16 hi/lo (coalesced float4 reads, packed bf16x2
// writes), then aligned ds_read_b128 fragments + split-bf16 MFMA.
// Wave quadrants: 4 waves each own a 96x96 quadrant (6x6 16-tiles).
// Partials (32 per batch) -> xpart; reduced by k_xred.
// ---------------------------------------------------------------------------
__global__ __launch_bounds__(256, 2) void k_xtx(const float* __restrict__ x,
                                                float* __restrict__ xpart)
{
    __shared__ __align__(16) __bf16 Th[192 * 40];
    __shared__ __align__(16) __bf16 Tl[192 * 40];
    const int t = threadIdx.x;
    const int lane = t & 63, wave = t >> 6;
    const int chunk = blockIdx.x;      // 32 chunks of 512 tokens
    const int b = blockIdx.y;
    const int n0 = chunk * 512;
    const int m16 = lane & 15, q = lane >> 4;
    const int rq = (wave & 1) * 6;     // row 16-ch-group base
    const int cq = (wave >> 1) * 6;    // col 16-ch-group base

    f32x4 acc[6][6];
#pragma unroll
    for (int i = 0; i < 6; ++i)
#pragma unroll
        for (int j = 0; j < 6; ++j)
#pragma unroll
            for (int r = 0; r < 4; ++r) acc[i][j][r] = 0.f;

    // staging decomposition: 3 units/thread; unit = (4-ch group, token pair)
    int u0 = t, u1 = t + 256, u2 = t + 512;
    const int ch4_0 = (u0 % 48) * 4, tk_0 = (u0 / 48) * 2;
    const int ch4_1 = (u1 % 48) * 4, tk_1 = (u1 / 48) * 2;
    const int ch4_2 = (u2 % 48) * 4, tk_2 = (u2 / 48) * 2;
    const float* xb = x + ((size_t)b * Ntok + n0) * 192;
    const float* p0 = xb + (size_t)tk_0 * 192 + ch4_0;
    const float* p1 = xb + (size_t)tk_1 * 192 + ch4_1;
    const float* p2 = xb + (size_t)tk_2 * 192 + ch4_2;
    const int o0 = ch4_0 * 40 + tk_0;
    const int o1 = ch4_1 * 40 + tk_1;
    const int o2 = ch4_2 * 40 + tk_2;

    for (int ks = 0; ks < 16; ++ks) {
        __syncthreads();
        {
            const float* pp[3] = { p0, p1, p2 };
            const int oo[3] = { o0, o1, o2 };
#pragma unroll
            for (int j = 0; j < 3; ++j) {
                const float* p = pp[j] + (size_t)ks * 32 * 192;
                float4 a = *(const float4*)p;
                float4 c = *(const float4*)(p + 192);
#pragma unroll
                for (int cix = 0; cix < 4; ++cix) {
                    float v0 = (&a.x)[cix], v1 = (&c.x)[cix];
                    __bf16 h0 = (__bf16)v0, h1 = (__bf16)v1;
                    __bf16 l0 = (__bf16)(v0 - (float)h0);
                    __bf16 l1 = (__bf16)(v1 - (float)h1);
                    int o = oo[j] + cix * 40;
                    bf16x2 hp; hp[0] = h0; hp[1] = h1;
                    bf16x2 lp; lp[0] = l0; lp[1] = l1;
                    *(bf16x2*)&Th[o] = hp;
                    *(bf16x2*)&Tl[o] = lp;
                }
            }
        }
        __syncthreads();

#pragma unroll
        for (int rb = 0; rb < 2; ++rb) {
            bf16x8 fah[3], fal[3];
#pragma unroll
            for (int g = 0; g < 3; ++g) {
                int o = ((rq + rb * 3 + g) * 16 + m16) * 40 + q * 8;
                fah[g] = *(const bf16x8*)&Th[o];
                fal[g] = *(const bf16x8*)&Tl[o];
            }
#pragma unroll
            for (int cb = 0; cb < 2; ++cb) {
                bf16x8 fbh[3], fbl[3];
#pragma unroll
                for (int g = 0; g < 3; ++g) {
                    int o = ((cq + cb * 3 + g) * 16 + m16) * 40 + q * 8;
                    fbh[g] = *(const bf16x8*)&Th[o];
                    fbl[g] = *(const bf16x8*)&Tl[o];
                }
#pragma unroll
                for (int ti = 0; ti < 3; ++ti)
#pragma unroll
                    for (int tj = 0; tj < 3; ++tj) {
                        f32x4& a = acc[rb * 3 + ti][cb * 3 + tj];
                        a = __builtin_amdgcn_mfma_f32_16x16x32_bf16(fah[ti], fbh[tj], a, 0, 0, 0);
                        a = __builtin_amdgcn_mfma_f32_16x16x32_bf16(fah[ti], fbl[tj], a, 0, 0, 0);
                        a = __builtin_amdgcn_mfma_f32_16x16x32_bf16(fal[ti], fbh[tj], a, 0, 0, 0);
                    }
            }
        }
    }
    float* op = xpart + ((size_t)b * 32 + chunk) * 36864;
#pragma unroll
    for (int ti = 0; ti < 6; ++ti)
#pragma unroll
        for (int tj = 0; tj < 6; ++tj) {
            const int row0 = (rq + ti) * 16 + q * 4;
            const int col = (cq + tj) * 16 + m16;
#pragma unroll
            for (int j = 0; j < 4; ++j)
                op[(size_t)(row0 + j) * 192 + col] = acc[ti][tj][j];
        }
}

// ---------------------------------------------------------------------------
// K_xred: reduce 32 chunk-partials -> XtX[b] (192x192 per batch).
// ---------------------------------------------------------------------------
__global__ __launch_bounds__(256) void k_xred(const float* __restrict__ xpart,
                                              float* __restrict__ XtX)
{
    const int b = blockIdx.y;
    const int e = blockIdx.x * 256 + threadIdx.x;   // 36864 = 144*256
    const float* p = xpart + (size_t)b * 32 * 36864 + e;
    float s = 0.f;
#pragma unroll
    for (int c = 0; c < 32; ++c) s += p[(size_t)c * 36864];
    XtX[(size_t)b * 36864 + e] = s;
}

// ---------------------------------------------------------------------------
// K_gram2: gram[b,h] = Wq_h^T XtX_b Wk_h; ssq_q[c] = Wq_c^T XtX Wq_c;
// ssq_k likewise. All fp32. Grid (B, HEADS).
// ---------------------------------------------------------------------------
__global__ __launch_bounds__(256) void k_gram2(const float* __restrict__ XtX,
                                               const float* __restrict__ w_qkv,
                                               float* __restrict__ gram,
                                               float* __restrict__ ssq_q,
                                               float* __restrict__ ssq_k)
{
    __shared__ float wq[192][24];
    __shared__ float wk[192][24];
    __shared__ float U[192][24];
    __shared__ float V[192][24];
    const int b = blockIdx.x, h = blockIdx.y, t = threadIdx.x;
    for (int e = t; e < 4608; e += 256) {
        int k = e / 24, c = e % 24;
        wq[k][c] = w_qkv[k * 576 + h * 24 + c];
        wk[k][c] = w_qkv[k * 576 + 192 + h * 24 + c];
    }
    __syncthreads();
    if (t < 192) {
        const float* xr = XtX + (size_t)b * 36864 + (size_t)t * 192;
        float u[24], v[24];
#pragma unroll
        for (int c = 0; c < 24; ++c) { u[c] = 0.f; v[c] = 0.f; }
        for (int k4 = 0; k4 < 48; ++k4) {
            float4 x4 = *(const float4*)(xr + k4 * 4);
#pragma unroll
            for (int kk = 0; kk < 4; ++kk) {
                float xv = (&x4.x)[kk];
                int k = k4 * 4 + kk;
#pragma unroll
                for (int c = 0; c < 24; ++c) {
                    u[c] = fmaf(xv, wq[k][c], u[c]);
                    v[c] = fmaf(xv, wk[k][c], v[c]);
                }
            }
        }
#pragma unroll
        for (int c = 0; c < 24; ++c) { U[t][c] = u[c]; V[t][c] = v[c]; }
    }
    __syncthreads();
    for (int o = t; o < 576; o += 256) {
        int c = o / 24, d = o % 24;
        float g = 0.f;
        for (int r = 0; r < 192; ++r) g = fmaf(wq[r][c], V[r][d], g);
        gram[(size_t)(b * NHEADS + h) * 576 + o] = g;
    }
    if (t < 24) {
        float s = 0.f;
        for (int r = 0; r < 192; ++r) s = fmaf(wq[r][t], U[r][t], s);
        ssq_q[b * Cc + h * HDim + t] = s;
    } else if (t < 48) {
        int c = t - 24;
        float s = 0.f;
        for (int r = 0; r < 192; ++r) s = fmaf(wk[r][c], V[r][c], s);
        ssq_k[b * Cc + h * HDim + c] = s;
    }
}

// ---------------------------------------------------------------------------
// K1 (v-only): v projection via split-bf16 MFMA. Block = 128 tokens x
// 192 v-cols. Output transposed to (B,C,N). Also accumulates per-channel
// v sums for the channel gate.
// ---------------------------------------------------------------------------
__global__ __launch_bounds__(256, 2) void k_qkv_mfma(const float* __restrict__ x,
                                                     const __bf16* __restrict__ wt,
                                                     float* __restrict__ vout,
                                                     float* __restrict__ vsum)
{
    __shared__ __align__(16) __bf16 Ah[128 * 40];
    __shared__ __align__(16) __bf16 Al[128 * 40];
    __shared__ __align__(16) __bf16 Bh[192 * 40];
    __shared__ __align__(16) __bf16 Bl[192 * 40];

    const int t = threadIdx.x;
    const int lane = t & 63, wave = t >> 6;
    const int n0 = blockIdx.x * 128;
    const int b = blockIdx.y;
    const int row_base = (wave & 1) * 64;
    const int col_base = (wave >> 1) * 96;
    const int m16 = lane & 15, q = lane >> 4;

    f32x4 acc[4][6];
#pragma unroll
    for (int rt = 0; rt < 4; ++rt)
#pragma unroll
        for (int ct = 0; ct < 6; ++ct)
#pragma unroll
            for (int j = 0; j < 4; ++j) acc[rt][ct][j] = 0.f;

    const int ar = t >> 1, ahalf = t & 1;
    const float* xrow = x + ((size_t)b * Ntok + n0 + ar) * Cc + ahalf * 16;

    for (int kc = 0; kc < 6; ++kc) {
        {
            const float4* xp4 = (const float4*)(xrow + kc * 32);
            float xv[16];
            float4 u;
            u = xp4[0]; xv[0] = u.x; xv[1] = u.y; xv[2]  = u.z; xv[3]  = u.w;
            u = xp4[1]; xv[4] = u.x; xv[5] = u.y; xv[6]  = u.z; xv[7]  = u.w;
            u = xp4[2]; xv[8] = u.x; xv[9] = u.y; xv[10] = u.z; xv[11] = u.w;
            u = xp4[3]; xv[12] = u.x; xv[13] = u.y; xv[14] = u.z; xv[15] = u.w;
            bf16x8 vh0, vh1, vl0, vl1;
            split8(xv, vh0, vl0);
            split8(xv + 8, vh1, vl1);
            const int o = ar * 40 + ahalf * 16;
            *(bf16x8*)&Ah[o] = vh0; *(bf16x8*)&Ah[o + 8] = vh1;
            *(bf16x8*)&Al[o] = vl0; *(bf16x8*)&Al[o + 8] = vl1;
        }
#pragma unroll
        for (int i = 0; i < 3; ++i) {
            int f = i * 256 + t;
            int n = f >> 2, k8 = (f & 3) << 3;
            const __bf16* src = wt + (size_t)n * 192 + kc * 32 + k8;
            bf16x8 vh = *(const bf16x8*)src;
            bf16x8 vl = *(const bf16x8*)(src + 36864);
            *(bf16x8*)&Bh[n * 40 + k8] = vh;
            *(bf16x8*)&Bl[n * 40 + k8] = vl;
        }
        __syncthreads();

        bf16x8 fah[4], fal[4], fbh[6], fbl[6];
#pragma unroll
        for (int rt = 0; rt < 4; ++rt) {
            int o = (row_base + rt * 16 + m16) * 40 + q * 8;
            fah[rt] = *(const bf16x8*)&Ah[o];
            fal[rt] = *(const bf16x8*)&Al[o];
        }
#pragma unroll
        for (int ct = 0; ct < 6; ++ct) {
            int o = (col_base + ct * 16 + m16) * 40 + q * 8;
            fbh[ct] = *(const bf16x8*)&Bh[o];
            fbl[ct] = *(const bf16x8*)&Bl[o];
        }
#pragma unroll
        for (int rt = 0; rt < 4; ++rt)
#pragma unroll
            for (int ct = 0; ct < 6; ++ct) {
                acc[rt][ct] = __builtin_amdgcn_mfma_f32_16x16x32_bf16(
                    fah[rt], fbh[ct], acc[rt][ct], 0, 0, 0);
                acc[rt][ct] = __builtin_amdgcn_mfma_f32_16x16x32_bf16(
                    fah[rt], fbl[ct], acc[rt][ct], 0, 0, 0);
                acc[rt][ct] = __builtin_amdgcn_mfma_f32_16x16x32_bf16(
                    fal[rt], fbh[ct], acc[rt][ct], 0, 0, 0);
            }
        __syncthreads();
    }

    const size_t obase = (size_t)b * Cc * (size_t)Ntok;
#pragma unroll
    for (int rt = 0; rt < 4; ++rt)
#pragma unroll
        for (int ct = 0; ct < 6; ++ct) {
            int token = n0 + row_base + rt * 16 + q * 4;
            int col = col_base + ct * 16 + m16;
            float4 o = make_float4(acc[rt][ct][0], acc[rt][ct][1],
                                   acc[rt][ct][2], acc[rt][ct][3]);
            *(float4*)(vout + obase + (size_t)col * Ntok + token) = o;
        }

#pragma unroll
    for (int ct = 0; ct < 6; ++ct) {
        float s = 0.f;
#pragma unroll
        for (int rt = 0; rt < 4; ++rt)
            s += acc[rt][ct][0] + acc[rt][ct][1] + acc[rt][ct][2] + acc[rt][ct][3];
        s += __shfl_xor(s, 16, 64);
        s += __shfl_xor(s, 32, 64);
        if (q == 0)
            atomicAdd(vsum + b * Cc + col_base + ct * 16 + m16, s);
    }
}

// K4: normalize gram -> softmax attn; pooled = attn @ vmean; channel-gate MLP.
__global__ __launch_bounds__(256) void k_attn(const float* __restrict__ gram,
                                              const float* __restrict__ ssq_q,
                                              const float* __restrict__ ssq_k,
                                              const float* __restrict__ temperature,
                                              const float* __restrict__ vmean,
                                              const float* __restrict__ ci_w1,
                                              const float* __restrict__ ci_b1,
                                              const float* __restrict__ bn2_g,
                                              const float* __restrict__ bn2_b,
                                              const float* __restrict__ bn2_m,
                                              const float* __restrict__ bn2_v,
                                              const float* __restrict__ ci_w2,
                                              const float* __restrict__ ci_b2,
                                              float* __restrict__ attn,
                                              float* __restrict__ sig_ch)
{
    __shared__ float pooled[192];
    __shared__ float cmv[24];
    const int b = blockIdx.x, t = threadIdx.x;
    if (t < 192) {
        int h = t / 24, c = t % 24;
        const float* gp = gram + (size_t)(b * NHEADS + h) * 576 + c * 24;
        float qn = fmaxf(sqrtf(ssq_q[b * Cc + h * HDim + c]), 1e-12f);
        float temp = temperature[h];
        float logit[24];
        float m = -1e30f;
#pragma unroll
        for (int d = 0; d < 24; ++d) {
            float kn = fmaxf(sqrtf(ssq_k[b * Cc + h * HDim + d]), 1e-12f);
            float l = gp[d] / (qn * kn) * temp;
            logit[d] = l; m = fmaxf(m, l);
        }
        float s = 0.f;
#pragma unroll
        for (int d = 0; d < 24; ++d) { float e = expf(logit[d] - m); logit[d] = e; s += e; }
        float inv = 1.f / s;
        float pool = 0.f;
        float* ap = attn + (size_t)(b * NHEADS + h) * 576 + c * 24;
#pragma unroll
        for (int d = 0; d < 24; ++d) {
            float a = logit[d] * inv;
            ap[d] = a;
            pool = fmaf(a, vmean[b * Cc + h * HDim + d], pool);
        }
        pooled[h * 24 + c] = pool * (1.0f / (float)Ntok);
    }
    __syncthreads();
    if (t < 24) {
        float z = ci_b1[t];
        for (int c = 0; c < 192; ++c) z = fmaf(ci_w1[t * 192 + c], pooled[c], z);
        float sc = bn2_g[t] / sqrtf(bn2_v[t] + EPSBN);
        z = z * sc + (bn2_b[t] - bn2_m[t] * sc);
        cmv[t] = gelu_f(z);
    }
    __syncthreads();
    if (t < 192) {
        float z = ci_b2[t];
#pragma unroll
        for (int o = 0; o < 24; ++o) z = fmaf(ci_w2[t * 24 + o], cmv[o], z);
        sig_ch[b * Cc + t] = sigmoid_f(z);
    }
}

// ---------------------------------------------------------------------------
// K4b: fold attention + channel gate into projection.
// ---------------------------------------------------------------------------
__global__ __launch_bounds__(192) void k_pprep(const float* __restrict__ attn,
                                               const float* __restrict__ sig_ch,
                                               const float* __restrict__ proj_w,
                                               __bf16* __restrict__ Pt)
{
    const int b = blockIdx.x, part = blockIdx.y, j = threadIdx.x;
    __bf16* base = Pt + (size_t)b * (2 * 73728);   // 73728 = 192*384
    if (part < 8) {
        const int h = part;
        __shared__ float at[576];
        for (int e = j; e < 576; e += 192) at[e] = attn[(size_t)(b * 8 + h) * 576 + e];
        __syncthreads();
        float pr[24];
#pragma unroll
        for (int cl = 0; cl < 24; ++cl) pr[cl] = proj_w[(h * 24 + cl) * 192 + j];
        float s[24];
#pragma unroll
        for (int d = 0; d < 24; ++d) s[d] = 0.f;
#pragma unroll
        for (int cl = 0; cl < 24; ++cl) {
            float a = pr[cl];
#pragma unroll
            for (int d = 0; d < 24; ++d) s[d] = fmaf(a, at[cl * 24 + d], s[d]);
        }
#pragma unroll
        for (int d = 0; d < 24; ++d) {
            float v = s[d];
            __bf16 hi = (__bf16)v;
            base[j * 384 + h * 24 + d] = hi;
            base[73728 + j * 384 + h * 24 + d] = (__bf16)(v - (float)hi);
        }
    } else {
        __shared__ float sch_s[192];
        sch_s[j] = sig_ch[b * Cc + j];
        __syncthreads();
        for (int ch = 0; ch < 192; ++ch) {
            float v = sch_s[ch] * proj_w[ch * 192 + j];
            __bf16 hi = (__bf16)v;
            base[j * 384 + 192 + ch] = hi;
            base[73728 + j * 384 + 192 + ch] = (__bf16)(v - (float)hi);
        }
    }
}

// ---------------------------------------------------------------------------
// K5 v3: depthwise 3x3 conv + BN1 + GELU, register-streaming (no LDS tile).
// Thread = (4-px quad, output row); per channel: 3 rows x (float4 + 2 edge
// scalars) from global, 9-tap conv in registers, float4 store.
// Grid (16, 24, B) = 3072 blocks, 256 thr.
// ---------------------------------------------------------------------------
__global__ __launch_bounds__(256) void k_conv(const float* __restrict__ vbuf,
                                              const float* __restrict__ dw_w,
                                              const float* __restrict__ dw_b,
                                              const float* __restrict__ bn1_g,
                                              const float* __restrict__ bn1_b,
                                              const float* __restrict__ bn1_m,
                                              const float* __restrict__ bn1_v,
                                              float* __restrict__ convx)
{
    __shared__ float dww[72];
    __shared__ float scl[8], shf[8];
    const int t = threadIdx.x;
    const int y0 = blockIdx.x * 8;
    const int ch0 = blockIdx.y * 8;
    const int b = blockIdx.z;

    if (t < 72) {
        dww[t] = dw_w[ch0 * 9 + t];
    } else if (t < 80) {
        int c = t - 72, ch = ch0 + c;
        float sc = bn1_g[ch] / sqrtf(bn1_v[ch] + EPSBN);
        scl[c] = sc;
        shf[c] = (dw_b[ch] - bn1_m[ch]) * sc + bn1_b[ch];
    }
    __syncthreads();

    const int xq = (t & 31) * 4;        // px base 0,4,...,124
    const int r = t >> 5;               // output row within tile 0..7
    const int gy = y0 + r;

#pragma unroll
    for (int ch = 0; ch < 8; ++ch) {
        const float* base = vbuf + ((size_t)b * Cc + ch0 + ch) * Ntok;
        float v[3][6];
#pragma unroll
        for (int dy = 0; dy < 3; ++dy) {
            int iy = gy - 1 + dy;
            if (iy >= 0 && iy < Him) {
                const float* rp = base + (size_t)iy * Wim;
                float4 m = *(const float4*)(rp + xq);
                v[dy][1] = m.x; v[dy][2] = m.y; v[dy][3] = m.z; v[dy][4] = m.w;
                v[dy][0] = (xq > 0) ? rp[xq - 1] : 0.f;
                v[dy][5] = (xq < 124) ? rp[xq + 4] : 0.f;
            } else {
#pragma unroll
                for (int i2 = 0; i2 < 6; ++i2) v[dy][i2] = 0.f;
            }
        }
        const float w0 = dww[ch * 9 + 0], w1 = dww[ch * 9 + 1], w2 = dww[ch * 9 + 2];
        const float w3 = dww[ch * 9 + 3], w4 = dww[ch * 9 + 4], w5 = dww[ch * 9 + 5];
        const float w6 = dww[ch * 9 + 6], w7 = dww[ch * 9 + 7], w8 = dww[ch * 9 + 8];
        const float sc = scl[ch], sh = shf[ch];
        float4 o;
#pragma unroll
        for (int p = 0; p < 4; ++p) {
            float s = v[0][p] * w0 + v[0][p + 1] * w1 + v[0][p + 2] * w2
                    + v[1][p] * w3 + v[1][p + 1] * w4 + v[1][p + 2] * w5
                    + v[2][p] * w6 + v[2][p + 1] * w7 + v[2][p + 2] * w8;
            (&o.x)[p] = gelu_f(s * sc + sh);
        }
        *(float4*)(convx + ((size_t)b * Cc + ch0 + ch) * Ntok
                   + (size_t)gy * Wim + xq) = o;
    }
}

// ---------------------------------------------------------------------------
// K6: fused epilogue GEMM + spatial-gate MLP.
// Phase 0 (kc 6..11): A = convx chunks; MFMA vs P_conv AND vs si_w1^T.
// Gate: dump to padded LDS, 128 threads do BN3+GELU+w2+sigmoid -> ssp_s.
// Phase 1 (kc 0..5): A = v chunks scaled by ssp_s[token]; MFMA vs P_att.
// ---------------------------------------------------------------------------
__global__ __launch_bounds__(256, 2) void k_final_mfma(const float* __restrict__ vbuf,
                                                       const float* __restrict__ convx,
                                                       const __bf16* __restrict__ Pt,
                                                       const float* __restrict__ si_w1,
                                                       const float* __restrict__ si_b1,
                                                       const float* __restrict__ bn3_g,
                                                       const float* __restrict__ bn3_b,
                                                       const float* __restrict__ bn3_m,
                                                       const float* __restrict__ bn3_v,
                                                       const float* __restrict__ si_w2,
                                                       const float* __restrict__ si_b2,
                                                       const float* __restrict__ proj_b,
                                                       float* __restrict__ out)
{
    __shared__ __align__(16) __bf16 Ah[128 * 40];
    __shared__ __align__(16) __bf16 Al[128 * 40];
    __shared__ __align__(16) __bf16 Bh[192 * 40];
    __shared__ __align__(16) __bf16 Bl[192 * 40];
    __shared__ float smbuf[128][17];
    __shared__ float ssp_s[128];

    const int t = threadIdx.x;
    const int lane = t & 63, wave = t >> 6;
    const int n0 = blockIdx.x * 128;
    const int b = blockIdx.y;
    const int row_base = (wave & 1) * 64;
    const int col_base = (wave >> 1) * 96;
    const int m16 = lane & 15, q = lane >> 4;

    const int an = t & 127;            // A-staging: token
    const int akh = (t >> 7) & 1;      // A-staging: 16-ch half
    const __bf16* ptb = Pt + (size_t)b * (2 * 73728);

    f32x4 acc[4][6];
#pragma unroll
    for (int rt = 0; rt < 4; ++rt)
#pragma unroll
        for (int ct = 0; ct < 6; ++ct)
#pragma unroll
            for (int j = 0; j < 4; ++j) acc[rt][ct][j] = 0.f;
    f32x4 accS[4];
#pragma unroll
    for (int rt = 0; rt < 4; ++rt)
#pragma unroll
        for (int j = 0; j < 4; ++j) accS[rt][j] = 0.f;

    for (int phase = 0; phase < 2; ++phase) {
        if (phase == 1) {
#pragma unroll
            for (int rt = 0; rt < 4; ++rt) {
                int row = row_base + rt * 16 + q * 4;
#pragma unroll
                for (int j = 0; j < 4; ++j)
                    smbuf[row + j][m16] = accS[rt][j];
            }
            __syncthreads();
            if (t < 128) {
                float sp = si_b2[0];
#pragma unroll
                for (int o = 0; o < 12; ++o) {
                    float z = smbuf[t][o] + si_b1[o];
                    float sc = bn3_g[o] / sqrtf(bn3_v[o] + EPSBN);
                    z = z * sc + (bn3_b[o] - bn3_m[o] * sc);
                    sp = fmaf(si_w2[o], gelu_f(z), sp);
                }
                ssp_s[t] = sigmoid_f(sp);
            }
            __syncthreads();
        }
        for (int ki = 0; ki < 6; ++ki) {
            const int kc = (phase == 0) ? (ki + 6) : ki;
            // ---- stage A ----
            {
                const int ch0 = ki * 32 + akh * 16;
                const float* src;
                float scale;
                if (phase == 0) {
                    src = convx + ((size_t)b * Cc + ch0) * Ntok + n0 + an;
                    scale = 1.f;
                } else {
                    src = vbuf + ((size_t)b * Cc + ch0) * Ntok + n0 + an;
                    scale = ssp_s[an];
                }
                float xv[16];
#pragma unroll
                for (int jj = 0; jj < 16; ++jj)
                    xv[jj] = src[(size_t)jj * Ntok] * scale;
                bf16x8 vh0, vl0, vh1, vl1;
                split8(xv, vh0, vl0);
                split8(xv + 8, vh1, vl1);
                const int o = an * 40 + akh * 16;
                *(bf16x8*)&Ah[o] = vh0; *(bf16x8*)&Ah[o + 8] = vh1;
                *(bf16x8*)&Al[o] = vl0; *(bf16x8*)&Al[o + 8] = vl1;
            }
            // ---- stage B from pre-split planes ----
#pragma unroll
            for (int i = 0; i < 3; ++i) {
                int f = i * 256 + t;
                int col = f >> 2, k8 = (f & 3) << 3;
                const __bf16* sp = ptb + (size_t)col * 384 + kc * 32 + k8;
                bf16x8 vh = *(const bf16x8*)sp;
                bf16x8 vl = *(const bf16x8*)(sp + 73728);
                *(bf16x8*)&Bh[col * 40 + k8] = vh;
                *(bf16x8*)&Bl[col * 40 + k8] = vl;
            }
            __syncthreads();

            bf16x8 fah[4], fal[4], fbh[6], fbl[6];
#pragma unroll
            for (int rt = 0; rt < 4; ++rt) {
                int o = (row_base + rt * 16 + m16) * 40 + q * 8;
                fah[rt] = *(const bf16x8*)&Ah[o];
                fal[rt] = *(const bf16x8*)&Al[o];
            }
#pragma unroll
            for (int ct = 0; ct < 6; ++ct) {
                int o = (col_base + ct * 16 + m16) * 40 + q * 8;
                fbh[ct] = *(const bf16x8*)&Bh[o];
            }
#pragma unroll
            for (int rt = 0; rt < 4; ++rt)
#pragma unroll
                for (int ct = 0; ct < 6; ++ct) {
                    acc[rt][ct] = __builtin_amdgcn_mfma_f32_16x16x32_bf16(
                        fah[rt], fbh[ct], acc[rt][ct], 0, 0, 0);
                    acc[rt][ct] = __builtin_amdgcn_mfma_f32_16x16x32_bf16(
                        fal[rt], fbh[ct], acc[rt][ct], 0, 0, 0);
                }
#pragma unroll
            for (int ct = 0; ct < 6; ++ct) {
                int o = (col_base + ct * 16 + m16) * 40 + q * 8;
                fbl[ct] = *(const bf16x8*)&Bl[o];
            }
#pragma unroll
            for (int rt = 0; rt < 4; ++rt)
#pragma unroll
                for (int ct = 0; ct < 6; ++ct)
                    acc[rt][ct] = __builtin_amdgcn_mfma_f32_16x16x32_bf16(
                        fah[rt], fbl[ct], acc[rt][ct], 0, 0, 0);

            if (phase == 0) {
                bf16x8 w1h, w1l;
                if (m16 < 12) {
                    const float* wp = si_w1 + m16 * 192 + ki * 32 + q * 8;
                    float wv[8];
                    float4 u0 = *(const float4*)wp, u1 = *(const float4*)(wp + 4);
                    wv[0] = u0.x; wv[1] = u0.y; wv[2] = u0.z; wv[3] = u0.w;
                    wv[4] = u1.x; wv[5] = u1.y; wv[6] = u1.z; wv[7] = u1.w;
                    split8(wv, w1h, w1l);
                } else {
#pragma unroll
                    for (int j = 0; j < 8; ++j) { w1h[j] = (__bf16)0.f; w1l[j] = (__bf16)0.f; }
                }
#pragma unroll
                for (int rt = 0; rt < 4; ++rt) {
                    accS[rt] = __builtin_amdgcn_mfma_f32_16x16x32_bf16(
                        fah[rt], w1h, accS[rt], 0, 0, 0);
                    accS[rt] = __builtin_amdgcn_mfma_f32_16x16x32_bf16(
                        fal[rt], w1h, accS[rt], 0, 0, 0);
                    accS[rt] = __builtin_amdgcn_mfma_f32_16x16x32_bf16(
                        fah[rt], w1l, accS[rt], 0, 0, 0);
                }
            }
            __syncthreads();
        }
    }

    // ---- epilogue: out (B,N,C) token-major + proj_b ----
    float* ob = out + ((size_t)b * Ntok + n0) * Cc;
#pragma unroll
    for (int ct = 0; ct < 6; ++ct) {
        const int col = col_base + ct * 16 + m16;
        const float pbv = proj_b[col];
#pragma unroll
        for (int rt = 0; rt < 4; ++rt) {
            const int row = row_base + rt * 16 + q * 4;
#pragma unroll
            for (int j = 0; j < 4; ++j)
                ob[(size_t)(row + j) * Cc + col] = acc[rt][ct][j] + pbv;
        }
    }
}

extern "C" void kernel_launch(void* const* d_in, const int* in_sizes, int n_in,
                              void* d_out, int out_size, void* d_ws, size_t ws_size,
                              hipStream_t stream)
{
    const float* x      = (const float*)d_in[0];
    const float* w_qkv  = (const float*)d_in[3];
    const float* temperature = (const float*)d_in[4];
    const float* dw_w   = (const float*)d_in[5];
    const float* dw_b   = (const float*)d_in[6];
    const float* bn1_g  = (const float*)d_in[7];
    const float* bn1_b  = (const float*)d_in[8];
    const float* bn1_m  = (const float*)d_in[9];
    const float* bn1_v  = (const float*)d_in[10];
    const float* ci_w1  = (const float*)d_in[11];
    const float* ci_b1  = (const float*)d_in[12];
    const float* bn2_g  = (const float*)d_in[13];
    const float* bn2_b  = (const float*)d_in[14];
    const float* bn2_m  = (const float*)d_in[15];
    const float* bn2_v  = (const float*)d_in[16];
    const float* ci_w2  = (const float*)d_in[17];
    const float* ci_b2  = (const float*)d_in[18];
    const float* si_w1  = (const float*)d_in[19];
    const float* si_b1  = (const float*)d_in[20];
    const float* bn3_g  = (const float*)d_in[21];
    const float* bn3_b  = (const float*)d_in[22];
    const float* bn3_m  = (const float*)d_in[23];
    const float* bn3_v  = (const float*)d_in[24];
    const float* si_w2  = (const float*)d_in[25];
    const float* si_b2  = (const float*)d_in[26];
    const float* proj_w = (const float*)d_in[27];
    const float* proj_b = (const float*)d_in[28];

    float* ws = (float*)d_ws;
    const size_t BCN = (size_t)Bb * Cc * Ntok;      // 25,165,824
    float* vbuf  = ws;
    float* convx = ws + BCN;
    __bf16* Pt   = (__bf16*)(ws + 2 * BCN);         // 8*2*73728 bf16 = 589824 f
    float* xpart = ws + 2 * BCN + 589824;           // 256*36864 = 9,437,184
    float* XtX   = xpart + 9437184;                 // 294,912
    float* gram  = XtX + 294912;                    // 36864
    float* ssq_q = gram + 36864;                    // 1536
    float* ssq_k = ssq_q + 1536;                    // 1536
    float* vmean = ssq_k + 1536;                    // 1536 (holds channel SUMS)
    float* attn  = vmean + 1536;                    // 36864
    float* sig_ch = attn + 36864;                   // 1536
    float* out = (float*)d_out;

    __bf16* wt = (__bf16*)(out + BCN - 36864);      // 73728 bf16 in out tail

    hipMemsetAsync(vmean, 0, 1536 * sizeof(float), stream);

    k_wprep<<<dim3(144), 256, 0, stream>>>(w_qkv, wt);
    k_xtx<<<dim3(32, Bb), 256, 0, stream>>>(x, xpart);
    k_xred<<<dim3(144, Bb), 256, 0, stream>>>(xpart, XtX);
    k_gram2<<<dim3(Bb, NHEADS), 256, 0, stream>>>(XtX, w_qkv, gram, ssq_q, ssq_k);
    k_qkv_mfma<<<dim3(Ntok / 128, Bb), 256, 0, stream>>>(x, wt, vbuf, vmean);
    k_attn<<<dim3(Bb), 256, 0, stream>>>(gram, ssq_q, ssq_k, temperature, vmean,
                                         ci_w1, ci_b1, bn2_g, bn2_b, bn2_m, bn2_v,
                                         ci_w2, ci_b2, attn, sig_ch);
    k_pprep<<<dim3(Bb, 9), 192, 0, stream>>>(attn, sig_ch, proj_w, Pt);
    k_conv<<<dim3(Him / 8, Cc / 8, Bb), 256, 0, stream>>>(
        vbuf, dw_w, dw_b, bn1_g, bn1_b, bn1_m, bn1_v, convx);
    k_final_mfma<<<dim3(Ntok / 128, Bb), 256, 0, stream>>>(
        vbuf, convx, Pt, si_w1, si_b1, bn3_g, bn3_b, bn3_m, bn3_v,
        si_w2, si_b2, proj_b, out);
}

// Round 5
// 529.517 us; speedup vs baseline: 1.3176x; 1.0568x over previous
//
#include <hip/hip_runtime.h>
#include <math.h>

// Problem constants (fixed by setup_inputs)
#define Bb 8
#define Cc 192
#define NHEADS 8
#define HDim 24
#define Him 128
#define Wim 128
#define Ntok 16384   // H*W
#define EPSBN 1e-5f

typedef __bf16 bf16x8 __attribute__((ext_vector_type(8)));
typedef __bf16 bf16x2 __attribute__((ext_vector_type(2)));
typedef float  f32x4  __attribute__((ext_vector_type(4)));

static __device__ __forceinline__ float gelu_f(float v) {
    return 0.5f * v * (1.0f + erff(v * 0.70710678118654752f));
}
static __device__ __forceinline__ float sigmoid_f(float v) {
    return 1.0f / (1.0f + expf(-v));
}
static __device__ __forceinline__ void split8(const float* xv, bf16x8& h8, bf16x8& l8) {
#pragma unroll
    for (int j = 0; j < 8; ++j) {
        float v = xv[j];
        __bf16 h = (__bf16)v;
        h8[j] = h;
        l8[j] = (__bf16)(v - (float)h);
    }
}

// ---------------------------------------------------------------------------
// K0: one-time prep: transpose v-part of w_qkv (192x192 fp32, cols 384..575)
// into bf16 hi/lo planes in [col][k] layout. Stored in tail of d_out.
// ---------------------------------------------------------------------------
__global__ __launch_bounds__(256) void k_wprep(const float* __restrict__ w,
                                               __bf16* __restrict__ wt)
{
    int idx = blockIdx.x * 256 + threadIdx.x;   // 192*192 = 36864 total
    if (idx >= 36864) return;
    int k = idx / 192, c = idx % 192;           // coalesced read over c
    float v = w[k * 576 + 384 + c];
    __bf16 h = (__bf16)v;
    __bf16 l = (__bf16)(v - (float)h);
    wt[c * 192 + k] = h;
    wt[36864 + c * 192 + k] = l;
}

// ---------------------------------------------------------------------------
// K_xtx v3: per-batch input Gram partials via LDS-transposed staging.
// v2 spilled acc[6][6] (144 f32) past the 256-VGPR launch-bounds cap ->
// scratch-bound, 0.37% occupancy, 179us. Now 512 thr / 8 waves, each wave
// owns a 96x48 quadrant (acc[6][3] = 72 VGPR, no spill). LDS transpose
// buffer uses a chunk-rotation swizzle to break the 24-way write conflicts:
// elem(ch,tok) = ch*40 + (((tok>>3)+(ch>>3))&3)*8 + (tok&7); reads use the
// same mapping (fragment = one 16B-aligned token octet).
// ---------------------------------------------------------------------------
__global__ __launch_bounds__(512, 2) void k_xtx(const float* __restrict__ x,
                                                float* __restrict__ xpart)
{
    __shared__ __align__(16) __bf16 Th[192 * 40];
    __shared__ __align__(16) __bf16 Tl[192 * 40];
    const int t = threadIdx.x;
    const int lane = t & 63, wave = t >> 6;   // 8 waves
    const int chunk = blockIdx.x;      // 32 chunks of 512 tokens
    const int b = blockIdx.y;
    const int n0 = chunk * 512;
    const int m16 = lane & 15, q = lane >> 4;
    const int rq = (wave & 1) * 6;     // row 16-ch-tile base (2 groups of 96)
    const int cq = (wave >> 1) * 3;    // col 16-ch-tile base (4 groups of 48)

    f32x4 acc[6][3];
#pragma unroll
    for (int i = 0; i < 6; ++i)
#pragma unroll
        for (int j = 0; j < 3; ++j)
#pragma unroll
            for (int r = 0; r < 4; ++r) acc[i][j][r] = 0.f;

    // staging units: u = (ch4-group, token-pair); 48*16 = 768 units.
    // thread t handles unit t; threads <256 also handle unit 512+t.
    const int ch4_0 = (t % 48) * 4, tk_0 = (t / 48) * 2;
    const int u1 = 512 + t;
    const int ch4_1 = (u1 % 48) * 4, tk_1 = (u1 / 48) * 2;
    const bool has2 = (t < 256);
    const float* xb = x + ((size_t)b * Ntok + n0) * 192;

    for (int ks = 0; ks < 16; ++ks) {
        __syncthreads();
        {
            const float* p = xb + (size_t)(ks * 32 + tk_0) * 192 + ch4_0;
            float4 a = *(const float4*)p;
            float4 c = *(const float4*)(p + 192);
#pragma unroll
            for (int cix = 0; cix < 4; ++cix) {
                int ch = ch4_0 + cix;
                float v0 = (&a.x)[cix], v1 = (&c.x)[cix];
                __bf16 h0 = (__bf16)v0, h1 = (__bf16)v1;
                __bf16 l0 = (__bf16)(v0 - (float)h0);
                __bf16 l1 = (__bf16)(v1 - (float)h1);
                int o = ch * 40 + ((((tk_0 >> 3) + (ch >> 3)) & 3) << 3) + (tk_0 & 7);
                bf16x2 hp; hp[0] = h0; hp[1] = h1;
                bf16x2 lp; lp[0] = l0; lp[1] = l1;
                *(bf16x2*)&Th[o] = hp;
                *(bf16x2*)&Tl[o] = lp;
            }
            if (has2) {
                const float* p2 = xb + (size_t)(ks * 32 + tk_1) * 192 + ch4_1;
                float4 a2 = *(const float4*)p2;
                float4 c2 = *(const float4*)(p2 + 192);
#pragma unroll
                for (int cix = 0; cix < 4; ++cix) {
                    int ch = ch4_1 + cix;
                    float v0 = (&a2.x)[cix], v1 = (&c2.x)[cix];
                    __bf16 h0 = (__bf16)v0, h1 = (__bf16)v1;
                    __bf16 l0 = (__bf16)(v0 - (float)h0);
                    __bf16 l1 = (__bf16)(v1 - (float)h1);
                    int o = ch * 40 + ((((tk_1 >> 3) + (ch >> 3)) & 3) << 3) + (tk_1 & 7);
                    bf16x2 hp; hp[0] = h0; hp[1] = h1;
                    bf16x2 lp; lp[0] = l0; lp[1] = l1;
                    *(bf16x2*)&Th[o] = hp;
                    *(bf16x2*)&Tl[o] = lp;
                }
            }
        }
        __syncthreads();

        bf16x8 fah[6], fal[6];
#pragma unroll
        for (int ti = 0; ti < 6; ++ti) {
            int ch = (rq + ti) * 16 + m16;
            int o = ch * 40 + (((q + (ch >> 3)) & 3) << 3);
            fah[ti] = *(const bf16x8*)&Th[o];
            fal[ti] = *(const bf16x8*)&Tl[o];
        }
#pragma unroll
        for (int tj = 0; tj < 3; ++tj) {
            int ch = (cq + tj) * 16 + m16;
            int o = ch * 40 + (((q + (ch >> 3)) & 3) << 3);
            bf16x8 fbh = *(const bf16x8*)&Th[o];
            bf16x8 fbl = *(const bf16x8*)&Tl[o];
#pragma unroll
            for (int ti = 0; ti < 6; ++ti) {
                f32x4& a = acc[ti][tj];
                a = __builtin_amdgcn_mfma_f32_16x16x32_bf16(fah[ti], fbh, a, 0, 0, 0);
                a = __builtin_amdgcn_mfma_f32_16x16x32_bf16(fah[ti], fbl, a, 0, 0, 0);
                a = __builtin_amdgcn_mfma_f32_16x16x32_bf16(fal[ti], fbh, a, 0, 0, 0);
            }
        }
    }
    float* op = xpart + ((size_t)b * 32 + chunk) * 36864;
#pragma unroll
    for (int ti = 0; ti < 6; ++ti)
#pragma unroll
        for (int tj = 0; tj < 3; ++tj) {
            const int row0 = (rq + ti) * 16 + q * 4;
            const int col = (cq + tj) * 16 + m16;
#pragma unroll
            for (int j = 0; j < 4; ++j)
                op[(size_t)(row0 + j) * 192 + col] = acc[ti][tj][j];
        }
}

// ---------------------------------------------------------------------------
// K_xred: reduce 32 chunk-partials -> XtX[b] (192x192 per batch).
// ---------------------------------------------------------------------------
__global__ __launch_bounds__(256) void k_xred(const float* __restrict__ xpart,
                                              float* __restrict__ XtX)
{
    const int b = blockIdx.y;
    const int e = blockIdx.x * 256 + threadIdx.x;   // 36864 = 144*256
    const float* p = xpart + (size_t)b * 32 * 36864 + e;
    float s = 0.f;
#pragma unroll
    for (int c = 0; c < 32; ++c) s += p[(size_t)c * 36864];
    XtX[(size_t)b * 36864 + e] = s;
}

// ---------------------------------------------------------------------------
// K_gram2: gram[b,h] = Wq_h^T XtX_b Wk_h; ssq_q[c] = Wq_c^T XtX Wq_c;
// ssq_k likewise. All fp32. Grid (B, HEADS).
// ---------------------------------------------------------------------------
__global__ __launch_bounds__(256) void k_gram2(const float* __restrict__ XtX,
                                               const float* __restrict__ w_qkv,
                                               float* __restrict__ gram,
                                               float* __restrict__ ssq_q,
                                               float* __restrict__ ssq_k)
{
    __shared__ float wq[192][24];
    __shared__ float wk[192][24];
    __shared__ float U[192][24];
    __shared__ float V[192][24];
    const int b = blockIdx.x, h = blockIdx.y, t = threadIdx.x;
    for (int e = t; e < 4608; e += 256) {
        int k = e / 24, c = e % 24;
        wq[k][c] = w_qkv[k * 576 + h * 24 + c];
        wk[k][c] = w_qkv[k * 576 + 192 + h * 24 + c];
    }
    __syncthreads();
    if (t < 192) {
        const float* xr = XtX + (size_t)b * 36864 + (size_t)t * 192;
        float u[24], v[24];
#pragma unroll
        for (int c = 0; c < 24; ++c) { u[c] = 0.f; v[c] = 0.f; }
        for (int k4 = 0; k4 < 48; ++k4) {
            float4 x4 = *(const float4*)(xr + k4 * 4);
#pragma unroll
            for (int kk = 0; kk < 4; ++kk) {
                float xv = (&x4.x)[kk];
                int k = k4 * 4 + kk;
#pragma unroll
                for (int c = 0; c < 24; ++c) {
                    u[c] = fmaf(xv, wq[k][c], u[c]);
                    v[c] = fmaf(xv, wk[k][c], v[c]);
                }
            }
        }
#pragma unroll
        for (int c = 0; c < 24; ++c) { U[t][c] = u[c]; V[t][c] = v[c]; }
    }
    __syncthreads();
    for (int o = t; o < 576; o += 256) {
        int c = o / 24, d = o % 24;
        float g = 0.f;
        for (int r = 0; r < 192; ++r) g = fmaf(wq[r][c], V[r][d], g);
        gram[(size_t)(b * NHEADS + h) * 576 + o] = g;
    }
    if (t < 24) {
        float s = 0.f;
        for (int r = 0; r < 192; ++r) s = fmaf(wq[r][t], U[r][t], s);
        ssq_q[b * Cc + h * HDim + t] = s;
    } else if (t < 48) {
        int c = t - 24;
        float s = 0.f;
        for (int r = 0; r < 192; ++r) s = fmaf(wk[r][c], V[r][c], s);
        ssq_k[b * Cc + h * HDim + c] = s;
    }
}

// ---------------------------------------------------------------------------
// K1 (v-only): v projection via split-bf16 MFMA. Block = 128 tokens x
// 192 v-cols. Output transposed to (B,C,N). Also accumulates per-channel
// v sums for the channel gate.
// ---------------------------------------------------------------------------
__global__ __launch_bounds__(256, 2) void k_qkv_mfma(const float* __restrict__ x,
                                                     const __bf16* __restrict__ wt,
                                                     float* __restrict__ vout,
                                                     float* __restrict__ vsum)
{
    __shared__ __align__(16) __bf16 Ah[128 * 40];
    __shared__ __align__(16) __bf16 Al[128 * 40];
    __shared__ __align__(16) __bf16 Bh[192 * 40];
    __shared__ __align__(16) __bf16 Bl[192 * 40];

    const int t = threadIdx.x;
    const int lane = t & 63, wave = t >> 6;
    const int n0 = blockIdx.x * 128;
    const int b = blockIdx.y;
    const int row_base = (wave & 1) * 64;
    const int col_base = (wave >> 1) * 96;
    const int m16 = lane & 15, q = lane >> 4;

    f32x4 acc[4][6];
#pragma unroll
    for (int rt = 0; rt < 4; ++rt)
#pragma unroll
        for (int ct = 0; ct < 6; ++ct)
#pragma unroll
            for (int j = 0; j < 4; ++j) acc[rt][ct][j] = 0.f;

    const int ar = t >> 1, ahalf = t & 1;
    const float* xrow = x + ((size_t)b * Ntok + n0 + ar) * Cc + ahalf * 16;

    for (int kc = 0; kc < 6; ++kc) {
        {
            const float4* xp4 = (const float4*)(xrow + kc * 32);
            float xv[16];
            float4 u;
            u = xp4[0]; xv[0] = u.x; xv[1] = u.y; xv[2]  = u.z; xv[3]  = u.w;
            u = xp4[1]; xv[4] = u.x; xv[5] = u.y; xv[6]  = u.z; xv[7]  = u.w;
            u = xp4[2]; xv[8] = u.x; xv[9] = u.y; xv[10] = u.z; xv[11] = u.w;
            u = xp4[3]; xv[12] = u.x; xv[13] = u.y; xv[14] = u.z; xv[15] = u.w;
            bf16x8 vh0, vh1, vl0, vl1;
            split8(xv, vh0, vl0);
            split8(xv + 8, vh1, vl1);
            const int o = ar * 40 + ahalf * 16;
            *(bf16x8*)&Ah[o] = vh0; *(bf16x8*)&Ah[o + 8] = vh1;
            *(bf16x8*)&Al[o] = vl0; *(bf16x8*)&Al[o + 8] = vl1;
        }
#pragma unroll
        for (int i = 0; i < 3; ++i) {
            int f = i * 256 + t;
            int n = f >> 2, k8 = (f & 3) << 3;
            const __bf16* src = wt + (size_t)n * 192 + kc * 32 + k8;
            bf16x8 vh = *(const bf16x8*)src;
            bf16x8 vl = *(const bf16x8*)(src + 36864);
            *(bf16x8*)&Bh[n * 40 + k8] = vh;
            *(bf16x8*)&Bl[n * 40 + k8] = vl;
        }
        __syncthreads();

        bf16x8 fah[4], fal[4], fbh[6], fbl[6];
#pragma unroll
        for (int rt = 0; rt < 4; ++rt) {
            int o = (row_base + rt * 16 + m16) * 40 + q * 8;
            fah[rt] = *(const bf16x8*)&Ah[o];
            fal[rt] = *(const bf16x8*)&Al[o];
        }
#pragma unroll
        for (int ct = 0; ct < 6; ++ct) {
            int o = (col_base + ct * 16 + m16) * 40 + q * 8;
            fbh[ct] = *(const bf16x8*)&Bh[o];
            fbl[ct] = *(const bf16x8*)&Bl[o];
        }
#pragma unroll
        for (int rt = 0; rt < 4; ++rt)
#pragma unroll
            for (int ct = 0; ct < 6; ++ct) {
                acc[rt][ct] = __builtin_amdgcn_mfma_f32_16x16x32_bf16(
                    fah[rt], fbh[ct], acc[rt][ct], 0, 0, 0);
                acc[rt][ct] = __builtin_amdgcn_mfma_f32_16x16x32_bf16(
                    fah[rt], fbl[ct], acc[rt][ct], 0, 0, 0);
                acc[rt][ct] = __builtin_amdgcn_mfma_f32_16x16x32_bf16(
                    fal[rt], fbh[ct], acc[rt][ct], 0, 0, 0);
            }
        __syncthreads();
    }

    const size_t obase = (size_t)b * Cc * (size_t)Ntok;
#pragma unroll
    for (int rt = 0; rt < 4; ++rt)
#pragma unroll
        for (int ct = 0; ct < 6; ++ct) {
            int token = n0 + row_base + rt * 16 + q * 4;
            int col = col_base + ct * 16 + m16;
            float4 o = make_float4(acc[rt][ct][0], acc[rt][ct][1],
                                   acc[rt][ct][2], acc[rt][ct][3]);
            *(float4*)(vout + obase + (size_t)col * Ntok + token) = o;
        }

#pragma unroll
    for (int ct = 0; ct < 6; ++ct) {
        float s = 0.f;
#pragma unroll
        for (int rt = 0; rt < 4; ++rt)
            s += acc[rt][ct][0] + acc[rt][ct][1] + acc[rt][ct][2] + acc[rt][ct][3];
        s += __shfl_xor(s, 16, 64);
        s += __shfl_xor(s, 32, 64);
        if (q == 0)
            atomicAdd(vsum + b * Cc + col_base + ct * 16 + m16, s);
    }
}

// K4: normalize gram -> softmax attn; pooled = attn @ vmean; channel-gate MLP.
__global__ __launch_bounds__(256) void k_attn(const float* __restrict__ gram,
                                              const float* __restrict__ ssq_q,
                                              const float* __restrict__ ssq_k,
                                              const float* __restrict__ temperature,
                                              const float* __restrict__ vmean,
                                              const float* __restrict__ ci_w1,
                                              const float* __restrict__ ci_b1,
                                              const float* __restrict__ bn2_g,
                                              const float* __restrict__ bn2_b,
                                              const float* __restrict__ bn2_m,
                                              const float* __restrict__ bn2_v,
                                              const float* __restrict__ ci_w2,
                                              const float* __restrict__ ci_b2,
                                              float* __restrict__ attn,
                                              float* __restrict__ sig_ch)
{
    __shared__ float pooled[192];
    __shared__ float cmv[24];
    const int b = blockIdx.x, t = threadIdx.x;
    if (t < 192) {
        int h = t / 24, c = t % 24;
        const float* gp = gram + (size_t)(b * NHEADS + h) * 576 + c * 24;
        float qn = fmaxf(sqrtf(ssq_q[b * Cc + h * HDim + c]), 1e-12f);
        float temp = temperature[h];
        float logit[24];
        float m = -1e30f;
#pragma unroll
        for (int d = 0; d < 24; ++d) {
            float kn = fmaxf(sqrtf(ssq_k[b * Cc + h * HDim + d]), 1e-12f);
            float l = gp[d] / (qn * kn) * temp;
            logit[d] = l; m = fmaxf(m, l);
        }
        float s = 0.f;
#pragma unroll
        for (int d = 0; d < 24; ++d) { float e = expf(logit[d] - m); logit[d] = e; s += e; }
        float inv = 1.f / s;
        float pool = 0.f;
        float* ap = attn + (size_t)(b * NHEADS + h) * 576 + c * 24;
#pragma unroll
        for (int d = 0; d < 24; ++d) {
            float a = logit[d] * inv;
            ap[d] = a;
            pool = fmaf(a, vmean[b * Cc + h * HDim + d], pool);
        }
        pooled[h * 24 + c] = pool * (1.0f / (float)Ntok);
    }
    __syncthreads();
    if (t < 24) {
        float z = ci_b1[t];
        for (int c = 0; c < 192; ++c) z = fmaf(ci_w1[t * 192 + c], pooled[c], z);
        float sc = bn2_g[t] / sqrtf(bn2_v[t] + EPSBN);
        z = z * sc + (bn2_b[t] - bn2_m[t] * sc);
        cmv[t] = gelu_f(z);
    }
    __syncthreads();
    if (t < 192) {
        float z = ci_b2[t];
#pragma unroll
        for (int o = 0; o < 24; ++o) z = fmaf(ci_w2[t * 24 + o], cmv[o], z);
        sig_ch[b * Cc + t] = sigmoid_f(z);
    }
}

// ---------------------------------------------------------------------------
// K4b: fold attention + channel gate into projection.
// ---------------------------------------------------------------------------
__global__ __launch_bounds__(192) void k_pprep(const float* __restrict__ attn,
                                               const float* __restrict__ sig_ch,
                                               const float* __restrict__ proj_w,
                                               __bf16* __restrict__ Pt)
{
    const int b = blockIdx.x, part = blockIdx.y, j = threadIdx.x;
    __bf16* base = Pt + (size_t)b * (2 * 73728);   // 73728 = 192*384
    if (part < 8) {
        const int h = part;
        __shared__ float at[576];
        for (int e = j; e < 576; e += 192) at[e] = attn[(size_t)(b * 8 + h) * 576 + e];
        __syncthreads();
        float pr[24];
#pragma unroll
        for (int cl = 0; cl < 24; ++cl) pr[cl] = proj_w[(h * 24 + cl) * 192 + j];
        float s[24];
#pragma unroll
        for (int d = 0; d < 24; ++d) s[d] = 0.f;
#pragma unroll
        for (int cl = 0; cl < 24; ++cl) {
            float a = pr[cl];
#pragma unroll
            for (int d = 0; d < 24; ++d) s[d] = fmaf(a, at[cl * 24 + d], s[d]);
        }
#pragma unroll
        for (int d = 0; d < 24; ++d) {
            float v = s[d];
            __bf16 hi = (__bf16)v;
            base[j * 384 + h * 24 + d] = hi;
            base[73728 + j * 384 + h * 24 + d] = (__bf16)(v - (float)hi);
        }
    } else {
        __shared__ float sch_s[192];
        sch_s[j] = sig_ch[b * Cc + j];
        __syncthreads();
        for (int ch = 0; ch < 192; ++ch) {
            float v = sch_s[ch] * proj_w[ch * 192 + j];
            __bf16 hi = (__bf16)v;
            base[j * 384 + 192 + ch] = hi;
            base[73728 + j * 384 + 192 + ch] = (__bf16)(v - (float)hi);
        }
    }
}

// ---------------------------------------------------------------------------
// K5 v3: depthwise 3x3 conv + BN1 + GELU, register-streaming (no LDS tile).
// ---------------------------------------------------------------------------
__global__ __launch_bounds__(256) void k_conv(const float* __restrict__ vbuf,
                                              const float* __restrict__ dw_w,
                                              const float* __restrict__ dw_b,
                                              const float* __restrict__ bn1_g,
                                              const float* __restrict__ bn1_b,
                                              const float* __restrict__ bn1_m,
                                              const float* __restrict__ bn1_v,
                                              float* __restrict__ convx)
{
    __shared__ float dww[72];
    __shared__ float scl[8], shf[8];
    const int t = threadIdx.x;
    const int y0 = blockIdx.x * 8;
    const int ch0 = blockIdx.y * 8;
    const int b = blockIdx.z;

    if (t < 72) {
        dww[t] = dw_w[ch0 * 9 + t];
    } else if (t < 80) {
        int c = t - 72, ch = ch0 + c;
        float sc = bn1_g[ch] / sqrtf(bn1_v[ch] + EPSBN);
        scl[c] = sc;
        shf[c] = (dw_b[ch] - bn1_m[ch]) * sc + bn1_b[ch];
    }
    __syncthreads();

    const int xq = (t & 31) * 4;        // px base 0,4,...,124
    const int r = t >> 5;               // output row within tile 0..7
    const int gy = y0 + r;

#pragma unroll
    for (int ch = 0; ch < 8; ++ch) {
        const float* base = vbuf + ((size_t)b * Cc + ch0 + ch) * Ntok;
        float v[3][6];
#pragma unroll
        for (int dy = 0; dy < 3; ++dy) {
            int iy = gy - 1 + dy;
            if (iy >= 0 && iy < Him) {
                const float* rp = base + (size_t)iy * Wim;
                float4 m = *(const float4*)(rp + xq);
                v[dy][1] = m.x; v[dy][2] = m.y; v[dy][3] = m.z; v[dy][4] = m.w;
                v[dy][0] = (xq > 0) ? rp[xq - 1] : 0.f;
                v[dy][5] = (xq < 124) ? rp[xq + 4] : 0.f;
            } else {
#pragma unroll
                for (int i2 = 0; i2 < 6; ++i2) v[dy][i2] = 0.f;
            }
        }
        const float w0 = dww[ch * 9 + 0], w1 = dww[ch * 9 + 1], w2 = dww[ch * 9 + 2];
        const float w3 = dww[ch * 9 + 3], w4 = dww[ch * 9 + 4], w5 = dww[ch * 9 + 5];
        const float w6 = dww[ch * 9 + 6], w7 = dww[ch * 9 + 7], w8 = dww[ch * 9 + 8];
        const float sc = scl[ch], sh = shf[ch];
        float4 o;
#pragma unroll
        for (int p = 0; p < 4; ++p) {
            float s = v[0][p] * w0 + v[0][p + 1] * w1 + v[0][p + 2] * w2
                    + v[1][p] * w3 + v[1][p + 1] * w4 + v[1][p + 2] * w5
                    + v[2][p] * w6 + v[2][p + 1] * w7 + v[2][p + 2] * w8;
            (&o.x)[p] = gelu_f(s * sc + sh);
        }
        *(float4*)(convx + ((size_t)b * Cc + ch0 + ch) * Ntok
                   + (size_t)gy * Wim + xq) = o;
    }
}

// ---------------------------------------------------------------------------
// K6: fused epilogue GEMM + spatial-gate MLP.
// ---------------------------------------------------------------------------
__global__ __launch_bounds__(256, 2) void k_final_mfma(const float* __restrict__ vbuf,
                                                       const float* __restrict__ convx,
                                                       const __bf16* __restrict__ Pt,
                                                       const float* __restrict__ si_w1,
                                                       const float* __restrict__ si_b1,
                                                       const float* __restrict__ bn3_g,
                                                       const float* __restrict__ bn3_b,
                                                       const float* __restrict__ bn3_m,
                                                       const float* __restrict__ bn3_v,
                                                       const float* __restrict__ si_w2,
                                                       const float* __restrict__ si_b2,
                                                       const float* __restrict__ proj_b,
                                                       float* __restrict__ out)
{
    __shared__ __align__(16) __bf16 Ah[128 * 40];
    __shared__ __align__(16) __bf16 Al[128 * 40];
    __shared__ __align__(16) __bf16 Bh[192 * 40];
    __shared__ __align__(16) __bf16 Bl[192 * 40];
    __shared__ float smbuf[128][17];
    __shared__ float ssp_s[128];

    const int t = threadIdx.x;
    const int lane = t & 63, wave = t >> 6;
    const int n0 = blockIdx.x * 128;
    const int b = blockIdx.y;
    const int row_base = (wave & 1) * 64;
    const int col_base = (wave >> 1) * 96;
    const int m16 = lane & 15, q = lane >> 4;

    const int an = t & 127;            // A-staging: token
    const int akh = (t >> 7) & 1;      // A-staging: 16-ch half
    const __bf16* ptb = Pt + (size_t)b * (2 * 73728);

    f32x4 acc[4][6];
#pragma unroll
    for (int rt = 0; rt < 4; ++rt)
#pragma unroll
        for (int ct = 0; ct < 6; ++ct)
#pragma unroll
            for (int j = 0; j < 4; ++j) acc[rt][ct][j] = 0.f;
    f32x4 accS[4];
#pragma unroll
    for (int rt = 0; rt < 4; ++rt)
#pragma unroll
        for (int j = 0; j < 4; ++j) accS[rt][j] = 0.f;

    for (int phase = 0; phase < 2; ++phase) {
        if (phase == 1) {
#pragma unroll
            for (int rt = 0; rt < 4; ++rt) {
                int row = row_base + rt * 16 + q * 4;
#pragma unroll
                for (int j = 0; j < 4; ++j)
                    smbuf[row + j][m16] = accS[rt][j];
            }
            __syncthreads();
            if (t < 128) {
                float sp = si_b2[0];
#pragma unroll
                for (int o = 0; o < 12; ++o) {
                    float z = smbuf[t][o] + si_b1[o];
                    float sc = bn3_g[o] / sqrtf(bn3_v[o] + EPSBN);
                    z = z * sc + (bn3_b[o] - bn3_m[o] * sc);
                    sp = fmaf(si_w2[o], gelu_f(z), sp);
                }
                ssp_s[t] = sigmoid_f(sp);
            }
            __syncthreads();
        }
        for (int ki = 0; ki < 6; ++ki) {
            const int kc = (phase == 0) ? (ki + 6) : ki;
            // ---- stage A ----
            {
                const int ch0 = ki * 32 + akh * 16;
                const float* src;
                float scale;
                if (phase == 0) {
                    src = convx + ((size_t)b * Cc + ch0) * Ntok + n0 + an;
                    scale = 1.f;
                } else {
                    src = vbuf + ((size_t)b * Cc + ch0) * Ntok + n0 + an;
                    scale = ssp_s[an];
                }
                float xv[16];
#pragma unroll
                for (int jj = 0; jj < 16; ++jj)
                    xv[jj] = src[(size_t)jj * Ntok] * scale;
                bf16x8 vh0, vl0, vh1, vl1;
                split8(xv, vh0, vl0);
                split8(xv + 8, vh1, vl1);
                const int o = an * 40 + akh * 16;
                *(bf16x8*)&Ah[o] = vh0; *(bf16x8*)&Ah[o + 8] = vh1;
                *(bf16x8*)&Al[o] = vl0; *(bf16x8*)&Al[o + 8] = vl1;
            }
            // ---- stage B from pre-split planes ----
#pragma unroll
            for (int i = 0; i < 3; ++i) {
                int f = i * 256 + t;
                int col = f >> 2, k8 = (f & 3) << 3;
                const __bf16* sp = ptb + (size_t)col * 384 + kc * 32 + k8;
                bf16x8 vh = *(const bf16x8*)sp;
                bf16x8 vl = *(const bf16x8*)(sp + 73728);
                *(bf16x8*)&Bh[col * 40 + k8] = vh;
                *(bf16x8*)&Bl[col * 40 + k8] = vl;
            }
            __syncthreads();

            bf16x8 fah[4], fal[4], fbh[6], fbl[6];
#pragma unroll
            for (int rt = 0; rt < 4; ++rt) {
                int o = (row_base + rt * 16 + m16) * 40 + q * 8;
                fah[rt] = *(const bf16x8*)&Ah[o];
                fal[rt] = *(const bf16x8*)&Al[o];
            }
#pragma unroll
            for (int ct = 0; ct < 6; ++ct) {
                int o = (col_base + ct * 16 + m16) * 40 + q * 8;
                fbh[ct] = *(const bf16x8*)&Bh[o];
            }
#pragma unroll
            for (int rt = 0; rt < 4; ++rt)
#pragma unroll
                for (int ct = 0; ct < 6; ++ct) {
                    acc[rt][ct] = __builtin_amdgcn_mfma_f32_16x16x32_bf16(
                        fah[rt], fbh[ct], acc[rt][ct], 0, 0, 0);
                    acc[rt][ct] = __builtin_amdgcn_mfma_f32_16x16x32_bf16(
                        fal[rt], fbh[ct], acc[rt][ct], 0, 0, 0);
                }
#pragma unroll
            for (int ct = 0; ct < 6; ++ct) {
                int o = (col_base + ct * 16 + m16) * 40 + q * 8;
                fbl[ct] = *(const bf16x8*)&Bl[o];
            }
#pragma unroll
            for (int rt = 0; rt < 4; ++rt)
#pragma unroll
                for (int ct = 0; ct < 6; ++ct)
                    acc[rt][ct] = __builtin_amdgcn_mfma_f32_16x16x32_bf16(
                        fah[rt], fbl[ct], acc[rt][ct], 0, 0, 0);

            if (phase == 0) {
                bf16x8 w1h, w1l;
                if (m16 < 12) {
                    const float* wp = si_w1 + m16 * 192 + ki * 32 + q * 8;
                    float wv[8];
                    float4 u0 = *(const float4*)wp, u1 = *(const float4*)(wp + 4);
                    wv[0] = u0.x; wv[1] = u0.y; wv[2] = u0.z; wv[3] = u0.w;
                    wv[4] = u1.x; wv[5] = u1.y; wv[6] = u1.z; wv[7] = u1.w;
                    split8(wv, w1h, w1l);
                } else {
#pragma unroll
                    for (int j = 0; j < 8; ++j) { w1h[j] = (__bf16)0.f; w1l[j] = (__bf16)0.f; }
                }
#pragma unroll
                for (int rt = 0; rt < 4; ++rt) {
                    accS[rt] = __builtin_amdgcn_mfma_f32_16x16x32_bf16(
                        fah[rt], w1h, accS[rt], 0, 0, 0);
                    accS[rt] = __builtin_amdgcn_mfma_f32_16x16x32_bf16(
                        fal[rt], w1h, accS[rt], 0, 0, 0);
                    accS[rt] = __builtin_amdgcn_mfma_f32_16x16x32_bf16(
                        fah[rt], w1l, accS[rt], 0, 0, 0);
                }
            }
            __syncthreads();
        }
    }

    // ---- epilogue: out (B,N,C) token-major + proj_b ----
    float* ob = out + ((size_t)b * Ntok + n0) * Cc;
#pragma unroll
    for (int ct = 0; ct < 6; ++ct) {
        const int col = col_base + ct * 16 + m16;
        const float pbv = proj_b[col];
#pragma unroll
        for (int rt = 0; rt < 4; ++rt) {
            const int row = row_base + rt * 16 + q * 4;
#pragma unroll
            for (int j = 0; j < 4; ++j)
                ob[(size_t)(row + j) * Cc + col] = acc[rt][ct][j] + pbv;
        }
    }
}

extern "C" void kernel_launch(void* const* d_in, const int* in_sizes, int n_in,
                              void* d_out, int out_size, void* d_ws, size_t ws_size,
                              hipStream_t stream)
{
    const float* x      = (const float*)d_in[0];
    const float* w_qkv  = (const float*)d_in[3];
    const float* temperature = (const float*)d_in[4];
    const float* dw_w   = (const float*)d_in[5];
    const float* dw_b   = (const float*)d_in[6];
    const float* bn1_g  = (const float*)d_in[7];
    const float* bn1_b  = (const float*)d_in[8];
    const float* bn1_m  = (const float*)d_in[9];
    const float* bn1_v  = (const float*)d_in[10];
    const float* ci_w1  = (const float*)d_in[11];
    const float* ci_b1  = (const float*)d_in[12];
    const float* bn2_g  = (const float*)d_in[13];
    const float* bn2_b  = (const float*)d_in[14];
    const float* bn2_m  = (const float*)d_in[15];
    const float* bn2_v  = (const float*)d_in[16];
    const float* ci_w2  = (const float*)d_in[17];
    const float* ci_b2  = (const float*)d_in[18];
    const float* si_w1  = (const float*)d_in[19];
    const float* si_b1  = (const float*)d_in[20];
    const float* bn3_g  = (const float*)d_in[21];
    const float* bn3_b  = (const float*)d_in[22];
    const float* bn3_m  = (const float*)d_in[23];
    const float* bn3_v  = (const float*)d_in[24];
    const float* si_w2  = (const float*)d_in[25];
    const float* si_b2  = (const float*)d_in[26];
    const float* proj_w = (const float*)d_in[27];
    const float* proj_b = (const float*)d_in[28];

    float* ws = (float*)d_ws;
    const size_t BCN = (size_t)Bb * Cc * Ntok;      // 25,165,824
    float* vbuf  = ws;
    float* convx = ws + BCN;
    __bf16* Pt   = (__bf16*)(ws + 2 * BCN);         // 8*2*73728 bf16 = 589824 f
    float* xpart = ws + 2 * BCN + 589824;           // 256*36864 = 9,437,184
    float* XtX   = xpart + 9437184;                 // 294,912
    float* gram  = XtX + 294912;                    // 36864
    float* ssq_q = gram + 36864;                    // 1536
    float* ssq_k = ssq_q + 1536;                    // 1536
    float* vmean = ssq_k + 1536;                    // 1536 (holds channel SUMS)
    float* attn  = vmean + 1536;                    // 36864
    float* sig_ch = attn + 36864;                   // 1536
    float* out = (float*)d_out;

    __bf16* wt = (__bf16*)(out + BCN - 36864);      // 73728 bf16 in out tail

    hipMemsetAsync(vmean, 0, 1536 * sizeof(float), stream);

    k_wprep<<<dim3(144), 256, 0, stream>>>(w_qkv, wt);
    k_xtx<<<dim3(32, Bb), 512, 0, stream>>>(x, xpart);
    k_xred<<<dim3(144, Bb), 256, 0, stream>>>(xpart, XtX);
    k_gram2<<<dim3(Bb, NHEADS), 256, 0, stream>>>(XtX, w_qkv, gram, ssq_q, ssq_k);
    k_qkv_mfma<<<dim3(Ntok / 128, Bb), 256, 0, stream>>>(x, wt, vbuf, vmean);
    k_attn<<<dim3(Bb), 256, 0, stream>>>(gram, ssq_q, ssq_k, temperature, vmean,
                                         ci_w1, ci_b1, bn2_g, bn2_b, bn2_m, bn2_v,
                                         ci_w2, ci_b2, attn, sig_ch);
    k_pprep<<<dim3(Bb, 9), 192, 0, stream>>>(attn, sig_ch, proj_w, Pt);
    k_conv<<<dim3(Him / 8, Cc / 8, Bb), 256, 0, stream>>>(
        vbuf, dw_w, dw_b, bn1_g, bn1_b, bn1_m, bn1_v, convx);
    k_final_mfma<<<dim3(Ntok / 128, Bb), 256, 0, stream>>>(
        vbuf, convx, Pt, si_w1, si_b1, bn3_g, bn3_b, bn3_m, bn3_v,
        si_w2, si_b2, proj_b, out);
}

// Round 6
// 509.760 us; speedup vs baseline: 1.3687x; 1.0388x over previous
//
#include <hip/hip_runtime.h>
#include <math.h>

// Problem constants (fixed by setup_inputs)
#define Bb 8
#define Cc 192
#define NHEADS 8
#define HDim 24
#define Him 128
#define Wim 128
#define Ntok 16384   // H*W
#define EPSBN 1e-5f

typedef __bf16 bf16x8 __attribute__((ext_vector_type(8)));
typedef __bf16 bf16x2 __attribute__((ext_vector_type(2)));
typedef float  f32x4  __attribute__((ext_vector_type(4)));

static __device__ __forceinline__ float gelu_f(float v) {
    return 0.5f * v * (1.0f + erff(v * 0.70710678118654752f));
}
static __device__ __forceinline__ float sigmoid_f(float v) {
    return 1.0f / (1.0f + expf(-v));
}
static __device__ __forceinline__ void split8(const float* xv, bf16x8& h8, bf16x8& l8) {
#pragma unroll
    for (int j = 0; j < 8; ++j) {
        float v = xv[j];
        __bf16 h = (__bf16)v;
        h8[j] = h;
        l8[j] = (__bf16)(v - (float)h);
    }
}

// ---------------------------------------------------------------------------
// K0: one-time prep: transpose v-part of w_qkv (192x192 fp32, cols 384..575)
// into bf16 hi/lo planes in [col][k] layout. Stored in tail of d_out.
// ---------------------------------------------------------------------------
__global__ __launch_bounds__(256) void k_wprep(const float* __restrict__ w,
                                               __bf16* __restrict__ wt)
{
    int idx = blockIdx.x * 256 + threadIdx.x;   // 192*192 = 36864 total
    if (idx >= 36864) return;
    int k = idx / 192, c = idx % 192;           // coalesced read over c
    float v = w[k * 576 + 384 + c];
    __bf16 h = (__bf16)v;
    __bf16 l = (__bf16)(v - (float)h);
    wt[c * 192 + k] = h;
    wt[36864 + c * 192 + k] = l;
}

// ---------------------------------------------------------------------------
// K_xtx v4: v3 + T14 register prefetch. Staging loads for step ks+1 are
// issued into registers right after the ds_writes of step ks; reg-destined
// global loads stay in flight across __syncthreads, so x-read latency hides
// under the MFMA section (this kernel runs 1 block/CU -> no cross-block
// cover, prefetch is the only latency-hiding available).
// ---------------------------------------------------------------------------
__global__ __launch_bounds__(512, 2) void k_xtx(const float* __restrict__ x,
                                                float* __restrict__ xpart)
{
    __shared__ __align__(16) __bf16 Th[192 * 40];
    __shared__ __align__(16) __bf16 Tl[192 * 40];
    const int t = threadIdx.x;
    const int lane = t & 63, wave = t >> 6;   // 8 waves
    const int chunk = blockIdx.x;      // 32 chunks of 512 tokens
    const int b = blockIdx.y;
    const int n0 = chunk * 512;
    const int m16 = lane & 15, q = lane >> 4;
    const int rq = (wave & 1) * 6;     // row 16-ch-tile base (2 groups of 96)
    const int cq = (wave >> 1) * 3;    // col 16-ch-tile base (4 groups of 48)

    f32x4 acc[6][3];
#pragma unroll
    for (int i = 0; i < 6; ++i)
#pragma unroll
        for (int j = 0; j < 3; ++j)
#pragma unroll
            for (int r = 0; r < 4; ++r) acc[i][j][r] = 0.f;

    // staging units: u = (ch4-group, token-pair); 48*16 = 768 units.
    const int ch4_0 = (t % 48) * 4, tk_0 = (t / 48) * 2;
    const int u1 = 512 + t;
    const int ch4_1 = (u1 % 48) * 4, tk_1 = (u1 / 48) * 2;
    const bool has2 = (t < 256);
    const float* xb = x + ((size_t)b * Ntok + n0) * 192;

    float4 a0, c0, a1, c1;
    {   // preload ks = 0
        const float* p = xb + (size_t)tk_0 * 192 + ch4_0;
        a0 = *(const float4*)p;
        c0 = *(const float4*)(p + 192);
        if (has2) {
            const float* p2 = xb + (size_t)tk_1 * 192 + ch4_1;
            a1 = *(const float4*)p2;
            c1 = *(const float4*)(p2 + 192);
        }
    }

    for (int ks = 0; ks < 16; ++ks) {
        __syncthreads();
        {   // write current regs to LDS (swizzled transpose layout)
#pragma unroll
            for (int cix = 0; cix < 4; ++cix) {
                int ch = ch4_0 + cix;
                float v0 = (&a0.x)[cix], v1 = (&c0.x)[cix];
                __bf16 h0 = (__bf16)v0, h1 = (__bf16)v1;
                __bf16 l0 = (__bf16)(v0 - (float)h0);
                __bf16 l1 = (__bf16)(v1 - (float)h1);
                int o = ch * 40 + ((((tk_0 >> 3) + (ch >> 3)) & 3) << 3) + (tk_0 & 7);
                bf16x2 hp; hp[0] = h0; hp[1] = h1;
                bf16x2 lp; lp[0] = l0; lp[1] = l1;
                *(bf16x2*)&Th[o] = hp;
                *(bf16x2*)&Tl[o] = lp;
            }
            if (has2) {
#pragma unroll
                for (int cix = 0; cix < 4; ++cix) {
                    int ch = ch4_1 + cix;
                    float v0 = (&a1.x)[cix], v1 = (&c1.x)[cix];
                    __bf16 h0 = (__bf16)v0, h1 = (__bf16)v1;
                    __bf16 l0 = (__bf16)(v0 - (float)h0);
                    __bf16 l1 = (__bf16)(v1 - (float)h1);
                    int o = ch * 40 + ((((tk_1 >> 3) + (ch >> 3)) & 3) << 3) + (tk_1 & 7);
                    bf16x2 hp; hp[0] = h0; hp[1] = h1;
                    bf16x2 lp; lp[0] = l0; lp[1] = l1;
                    *(bf16x2*)&Th[o] = hp;
                    *(bf16x2*)&Tl[o] = lp;
                }
            }
        }
        if (ks < 15) {   // prefetch ks+1 into regs (flies across barriers)
            const float* p = xb + (size_t)((ks + 1) * 32 + tk_0) * 192 + ch4_0;
            a0 = *(const float4*)p;
            c0 = *(const float4*)(p + 192);
            if (has2) {
                const float* p2 = xb + (size_t)((ks + 1) * 32 + tk_1) * 192 + ch4_1;
                a1 = *(const float4*)p2;
                c1 = *(const float4*)(p2 + 192);
            }
        }
        __syncthreads();

        bf16x8 fah[6], fal[6];
#pragma unroll
        for (int ti = 0; ti < 6; ++ti) {
            int ch = (rq + ti) * 16 + m16;
            int o = ch * 40 + (((q + (ch >> 3)) & 3) << 3);
            fah[ti] = *(const bf16x8*)&Th[o];
            fal[ti] = *(const bf16x8*)&Tl[o];
        }
#pragma unroll
        for (int tj = 0; tj < 3; ++tj) {
            int ch = (cq + tj) * 16 + m16;
            int o = ch * 40 + (((q + (ch >> 3)) & 3) << 3);
            bf16x8 fbh = *(const bf16x8*)&Th[o];
            bf16x8 fbl = *(const bf16x8*)&Tl[o];
#pragma unroll
            for (int ti = 0; ti < 6; ++ti) {
                f32x4& a = acc[ti][tj];
                a = __builtin_amdgcn_mfma_f32_16x16x32_bf16(fah[ti], fbh, a, 0, 0, 0);
                a = __builtin_amdgcn_mfma_f32_16x16x32_bf16(fah[ti], fbl, a, 0, 0, 0);
                a = __builtin_amdgcn_mfma_f32_16x16x32_bf16(fal[ti], fbh, a, 0, 0, 0);
            }
        }
    }
    float* op = xpart + ((size_t)b * 32 + chunk) * 36864;
#pragma unroll
    for (int ti = 0; ti < 6; ++ti)
#pragma unroll
        for (int tj = 0; tj < 3; ++tj) {
            const int row0 = (rq + ti) * 16 + q * 4;
            const int col = (cq + tj) * 16 + m16;
#pragma unroll
            for (int j = 0; j < 4; ++j)
                op[(size_t)(row0 + j) * 192 + col] = acc[ti][tj][j];
        }
}

// ---------------------------------------------------------------------------
// K_xred: reduce 32 chunk-partials -> XtX[b] (192x192 per batch).
// ---------------------------------------------------------------------------
__global__ __launch_bounds__(256) void k_xred(const float* __restrict__ xpart,
                                              float* __restrict__ XtX)
{
    const int b = blockIdx.y;
    const int e = blockIdx.x * 256 + threadIdx.x;   // 36864 = 144*256
    const float* p = xpart + (size_t)b * 32 * 36864 + e;
    float s = 0.f;
#pragma unroll
    for (int c = 0; c < 32; ++c) s += p[(size_t)c * 36864];
    XtX[(size_t)b * 36864 + e] = s;
}

// ---------------------------------------------------------------------------
// K_gram2: gram[b,h] = Wq_h^T XtX_b Wk_h; ssq_q[c] = Wq_c^T XtX Wq_c;
// ssq_k likewise. All fp32. Grid (B, HEADS).
// ---------------------------------------------------------------------------
__global__ __launch_bounds__(256) void k_gram2(const float* __restrict__ XtX,
                                               const float* __restrict__ w_qkv,
                                               float* __restrict__ gram,
                                               float* __restrict__ ssq_q,
                                               float* __restrict__ ssq_k)
{
    __shared__ float wq[192][24];
    __shared__ float wk[192][24];
    __shared__ float U[192][24];
    __shared__ float V[192][24];
    const int b = blockIdx.x, h = blockIdx.y, t = threadIdx.x;
    for (int e = t; e < 4608; e += 256) {
        int k = e / 24, c = e % 24;
        wq[k][c] = w_qkv[k * 576 + h * 24 + c];
        wk[k][c] = w_qkv[k * 576 + 192 + h * 24 + c];
    }
    __syncthreads();
    if (t < 192) {
        const float* xr = XtX + (size_t)b * 36864 + (size_t)t * 192;
        float u[24], v[24];
#pragma unroll
        for (int c = 0; c < 24; ++c) { u[c] = 0.f; v[c] = 0.f; }
        for (int k4 = 0; k4 < 48; ++k4) {
            float4 x4 = *(const float4*)(xr + k4 * 4);
#pragma unroll
            for (int kk = 0; kk < 4; ++kk) {
                float xv = (&x4.x)[kk];
                int k = k4 * 4 + kk;
#pragma unroll
                for (int c = 0; c < 24; ++c) {
                    u[c] = fmaf(xv, wq[k][c], u[c]);
                    v[c] = fmaf(xv, wk[k][c], v[c]);
                }
            }
        }
#pragma unroll
        for (int c = 0; c < 24; ++c) { U[t][c] = u[c]; V[t][c] = v[c]; }
    }
    __syncthreads();
    for (int o = t; o < 576; o += 256) {
        int c = o / 24, d = o % 24;
        float g = 0.f;
        for (int r = 0; r < 192; ++r) g = fmaf(wq[r][c], V[r][d], g);
        gram[(size_t)(b * NHEADS + h) * 576 + o] = g;
    }
    if (t < 24) {
        float s = 0.f;
        for (int r = 0; r < 192; ++r) s = fmaf(wq[r][t], U[r][t], s);
        ssq_q[b * Cc + h * HDim + t] = s;
    } else if (t < 48) {
        int c = t - 24;
        float s = 0.f;
        for (int r = 0; r < 192; ++r) s = fmaf(wk[r][c], V[r][c], s);
        ssq_k[b * Cc + h * HDim + c] = s;
    }
}

// ---------------------------------------------------------------------------
// K1 (v-only) v2: + T14 register prefetch of the next kc's x rows.
// ---------------------------------------------------------------------------
__global__ __launch_bounds__(256, 2) void k_qkv_mfma(const float* __restrict__ x,
                                                     const __bf16* __restrict__ wt,
                                                     float* __restrict__ vout,
                                                     float* __restrict__ vsum)
{
    __shared__ __align__(16) __bf16 Ah[128 * 40];
    __shared__ __align__(16) __bf16 Al[128 * 40];
    __shared__ __align__(16) __bf16 Bh[192 * 40];
    __shared__ __align__(16) __bf16 Bl[192 * 40];

    const int t = threadIdx.x;
    const int lane = t & 63, wave = t >> 6;
    const int n0 = blockIdx.x * 128;
    const int b = blockIdx.y;
    const int row_base = (wave & 1) * 64;
    const int col_base = (wave >> 1) * 96;
    const int m16 = lane & 15, q = lane >> 4;

    f32x4 acc[4][6];
#pragma unroll
    for (int rt = 0; rt < 4; ++rt)
#pragma unroll
        for (int ct = 0; ct < 6; ++ct)
#pragma unroll
            for (int j = 0; j < 4; ++j) acc[rt][ct][j] = 0.f;

    const int ar = t >> 1, ahalf = t & 1;
    const float* xrow = x + ((size_t)b * Ntok + n0 + ar) * Cc + ahalf * 16;

    float4 pa[4];
    {   // preload kc = 0
        const float4* xp4 = (const float4*)xrow;
        pa[0] = xp4[0]; pa[1] = xp4[1]; pa[2] = xp4[2]; pa[3] = xp4[3];
    }

    for (int kc = 0; kc < 6; ++kc) {
        {   // stage A from prefetched regs
            float xv[16];
            xv[0]  = pa[0].x; xv[1]  = pa[0].y; xv[2]  = pa[0].z; xv[3]  = pa[0].w;
            xv[4]  = pa[1].x; xv[5]  = pa[1].y; xv[6]  = pa[1].z; xv[7]  = pa[1].w;
            xv[8]  = pa[2].x; xv[9]  = pa[2].y; xv[10] = pa[2].z; xv[11] = pa[2].w;
            xv[12] = pa[3].x; xv[13] = pa[3].y; xv[14] = pa[3].z; xv[15] = pa[3].w;
            bf16x8 vh0, vh1, vl0, vl1;
            split8(xv, vh0, vl0);
            split8(xv + 8, vh1, vl1);
            const int o = ar * 40 + ahalf * 16;
            *(bf16x8*)&Ah[o] = vh0; *(bf16x8*)&Ah[o + 8] = vh1;
            *(bf16x8*)&Al[o] = vl0; *(bf16x8*)&Al[o + 8] = vl1;
        }
#pragma unroll
        for (int i = 0; i < 3; ++i) {
            int f = i * 256 + t;
            int n = f >> 2, k8 = (f & 3) << 3;
            const __bf16* src = wt + (size_t)n * 192 + kc * 32 + k8;
            bf16x8 vh = *(const bf16x8*)src;
            bf16x8 vl = *(const bf16x8*)(src + 36864);
            *(bf16x8*)&Bh[n * 40 + k8] = vh;
            *(bf16x8*)&Bl[n * 40 + k8] = vl;
        }
        if (kc < 5) {   // prefetch next kc's A rows (flies across barriers)
            const float4* nx = (const float4*)(xrow + (kc + 1) * 32);
            pa[0] = nx[0]; pa[1] = nx[1]; pa[2] = nx[2]; pa[3] = nx[3];
        }
        __syncthreads();

        bf16x8 fah[4], fal[4], fbh[6], fbl[6];
#pragma unroll
        for (int rt = 0; rt < 4; ++rt) {
            int o = (row_base + rt * 16 + m16) * 40 + q * 8;
            fah[rt] = *(const bf16x8*)&Ah[o];
            fal[rt] = *(const bf16x8*)&Al[o];
        }
#pragma unroll
        for (int ct = 0; ct < 6; ++ct) {
            int o = (col_base + ct * 16 + m16) * 40 + q * 8;
            fbh[ct] = *(const bf16x8*)&Bh[o];
            fbl[ct] = *(const bf16x8*)&Bl[o];
        }
#pragma unroll
        for (int rt = 0; rt < 4; ++rt)
#pragma unroll
            for (int ct = 0; ct < 6; ++ct) {
                acc[rt][ct] = __builtin_amdgcn_mfma_f32_16x16x32_bf16(
                    fah[rt], fbh[ct], acc[rt][ct], 0, 0, 0);
                acc[rt][ct] = __builtin_amdgcn_mfma_f32_16x16x32_bf16(
                    fah[rt], fbl[ct], acc[rt][ct], 0, 0, 0);
                acc[rt][ct] = __builtin_amdgcn_mfma_f32_16x16x32_bf16(
                    fal[rt], fbh[ct], acc[rt][ct], 0, 0, 0);
            }
        __syncthreads();
    }

    const size_t obase = (size_t)b * Cc * (size_t)Ntok;
#pragma unroll
    for (int rt = 0; rt < 4; ++rt)
#pragma unroll
        for (int ct = 0; ct < 6; ++ct) {
            int token = n0 + row_base + rt * 16 + q * 4;
            int col = col_base + ct * 16 + m16;
            float4 o = make_float4(acc[rt][ct][0], acc[rt][ct][1],
                                   acc[rt][ct][2], acc[rt][ct][3]);
            *(float4*)(vout + obase + (size_t)col * Ntok + token) = o;
        }

#pragma unroll
    for (int ct = 0; ct < 6; ++ct) {
        float s = 0.f;
#pragma unroll
        for (int rt = 0; rt < 4; ++rt)
            s += acc[rt][ct][0] + acc[rt][ct][1] + acc[rt][ct][2] + acc[rt][ct][3];
        s += __shfl_xor(s, 16, 64);
        s += __shfl_xor(s, 32, 64);
        if (q == 0)
            atomicAdd(vsum + b * Cc + col_base + ct * 16 + m16, s);
    }
}

// K4: normalize gram -> softmax attn; pooled = attn @ vmean; channel-gate MLP.
__global__ __launch_bounds__(256) void k_attn(const float* __restrict__ gram,
                                              const float* __restrict__ ssq_q,
                                              const float* __restrict__ ssq_k,
                                              const float* __restrict__ temperature,
                                              const float* __restrict__ vmean,
                                              const float* __restrict__ ci_w1,
                                              const float* __restrict__ ci_b1,
                                              const float* __restrict__ bn2_g,
                                              const float* __restrict__ bn2_b,
                                              const float* __restrict__ bn2_m,
                                              const float* __restrict__ bn2_v,
                                              const float* __restrict__ ci_w2,
                                              const float* __restrict__ ci_b2,
                                              float* __restrict__ attn,
                                              float* __restrict__ sig_ch)
{
    __shared__ float pooled[192];
    __shared__ float cmv[24];
    const int b = blockIdx.x, t = threadIdx.x;
    if (t < 192) {
        int h = t / 24, c = t % 24;
        const float* gp = gram + (size_t)(b * NHEADS + h) * 576 + c * 24;
        float qn = fmaxf(sqrtf(ssq_q[b * Cc + h * HDim + c]), 1e-12f);
        float temp = temperature[h];
        float logit[24];
        float m = -1e30f;
#pragma unroll
        for (int d = 0; d < 24; ++d) {
            float kn = fmaxf(sqrtf(ssq_k[b * Cc + h * HDim + d]), 1e-12f);
            float l = gp[d] / (qn * kn) * temp;
            logit[d] = l; m = fmaxf(m, l);
        }
        float s = 0.f;
#pragma unroll
        for (int d = 0; d < 24; ++d) { float e = expf(logit[d] - m); logit[d] = e; s += e; }
        float inv = 1.f / s;
        float pool = 0.f;
        float* ap = attn + (size_t)(b * NHEADS + h) * 576 + c * 24;
#pragma unroll
        for (int d = 0; d < 24; ++d) {
            float a = logit[d] * inv;
            ap[d] = a;
            pool = fmaf(a, vmean[b * Cc + h * HDim + d], pool);
        }
        pooled[h * 24 + c] = pool * (1.0f / (float)Ntok);
    }
    __syncthreads();
    if (t < 24) {
        float z = ci_b1[t];
        for (int c = 0; c < 192; ++c) z = fmaf(ci_w1[t * 192 + c], pooled[c], z);
        float sc = bn2_g[t] / sqrtf(bn2_v[t] + EPSBN);
        z = z * sc + (bn2_b[t] - bn2_m[t] * sc);
        cmv[t] = gelu_f(z);
    }
    __syncthreads();
    if (t < 192) {
        float z = ci_b2[t];
#pragma unroll
        for (int o = 0; o < 24; ++o) z = fmaf(ci_w2[t * 24 + o], cmv[o], z);
        sig_ch[b * Cc + t] = sigmoid_f(z);
    }
}

// ---------------------------------------------------------------------------
// K4b: fold attention + channel gate into projection.
// ---------------------------------------------------------------------------
__global__ __launch_bounds__(192) void k_pprep(const float* __restrict__ attn,
                                               const float* __restrict__ sig_ch,
                                               const float* __restrict__ proj_w,
                                               __bf16* __restrict__ Pt)
{
    const int b = blockIdx.x, part = blockIdx.y, j = threadIdx.x;
    __bf16* base = Pt + (size_t)b * (2 * 73728);   // 73728 = 192*384
    if (part < 8) {
        const int h = part;
        __shared__ float at[576];
        for (int e = j; e < 576; e += 192) at[e] = attn[(size_t)(b * 8 + h) * 576 + e];
        __syncthreads();
        float pr[24];
#pragma unroll
        for (int cl = 0; cl < 24; ++cl) pr[cl] = proj_w[(h * 24 + cl) * 192 + j];
        float s[24];
#pragma unroll
        for (int d = 0; d < 24; ++d) s[d] = 0.f;
#pragma unroll
        for (int cl = 0; cl < 24; ++cl) {
            float a = pr[cl];
#pragma unroll
            for (int d = 0; d < 24; ++d) s[d] = fmaf(a, at[cl * 24 + d], s[d]);
        }
#pragma unroll
        for (int d = 0; d < 24; ++d) {
            float v = s[d];
            __bf16 hi = (__bf16)v;
            base[j * 384 + h * 24 + d] = hi;
            base[73728 + j * 384 + h * 24 + d] = (__bf16)(v - (float)hi);
        }
    } else {
        __shared__ float sch_s[192];
        sch_s[j] = sig_ch[b * Cc + j];
        __syncthreads();
        for (int ch = 0; ch < 192; ++ch) {
            float v = sch_s[ch] * proj_w[ch * 192 + j];
            __bf16 hi = (__bf16)v;
            base[j * 384 + 192 + ch] = hi;
            base[73728 + j * 384 + 192 + ch] = (__bf16)(v - (float)hi);
        }
    }
}

// ---------------------------------------------------------------------------
// K5 v3: depthwise 3x3 conv + BN1 + GELU, register-streaming (no LDS tile).
// ---------------------------------------------------------------------------
__global__ __launch_bounds__(256) void k_conv(const float* __restrict__ vbuf,
                                              const float* __restrict__ dw_w,
                                              const float* __restrict__ dw_b,
                                              const float* __restrict__ bn1_g,
                                              const float* __restrict__ bn1_b,
                                              const float* __restrict__ bn1_m,
                                              const float* __restrict__ bn1_v,
                                              float* __restrict__ convx)
{
    __shared__ float dww[72];
    __shared__ float scl[8], shf[8];
    const int t = threadIdx.x;
    const int y0 = blockIdx.x * 8;
    const int ch0 = blockIdx.y * 8;
    const int b = blockIdx.z;

    if (t < 72) {
        dww[t] = dw_w[ch0 * 9 + t];
    } else if (t < 80) {
        int c = t - 72, ch = ch0 + c;
        float sc = bn1_g[ch] / sqrtf(bn1_v[ch] + EPSBN);
        scl[c] = sc;
        shf[c] = (dw_b[ch] - bn1_m[ch]) * sc + bn1_b[ch];
    }
    __syncthreads();

    const int xq = (t & 31) * 4;        // px base 0,4,...,124
    const int r = t >> 5;               // output row within tile 0..7
    const int gy = y0 + r;

#pragma unroll
    for (int ch = 0; ch < 8; ++ch) {
        const float* base = vbuf + ((size_t)b * Cc + ch0 + ch) * Ntok;
        float v[3][6];
#pragma unroll
        for (int dy = 0; dy < 3; ++dy) {
            int iy = gy - 1 + dy;
            if (iy >= 0 && iy < Him) {
                const float* rp = base + (size_t)iy * Wim;
                float4 m = *(const float4*)(rp + xq);
                v[dy][1] = m.x; v[dy][2] = m.y; v[dy][3] = m.z; v[dy][4] = m.w;
                v[dy][0] = (xq > 0) ? rp[xq - 1] : 0.f;
                v[dy][5] = (xq < 124) ? rp[xq + 4] : 0.f;
            } else {
#pragma unroll
                for (int i2 = 0; i2 < 6; ++i2) v[dy][i2] = 0.f;
            }
        }
        const float w0 = dww[ch * 9 + 0], w1 = dww[ch * 9 + 1], w2 = dww[ch * 9 + 2];
        const float w3 = dww[ch * 9 + 3], w4 = dww[ch * 9 + 4], w5 = dww[ch * 9 + 5];
        const float w6 = dww[ch * 9 + 6], w7 = dww[ch * 9 + 7], w8 = dww[ch * 9 + 8];
        const float sc = scl[ch], sh = shf[ch];
        float4 o;
#pragma unroll
        for (int p = 0; p < 4; ++p) {
            float s = v[0][p] * w0 + v[0][p + 1] * w1 + v[0][p + 2] * w2
                    + v[1][p] * w3 + v[1][p + 1] * w4 + v[1][p + 2] * w5
                    + v[2][p] * w6 + v[2][p + 1] * w7 + v[2][p + 2] * w8;
            (&o.x)[p] = gelu_f(s * sc + sh);
        }
        *(float4*)(convx + ((size_t)b * Cc + ch0 + ch) * Ntok
                   + (size_t)gy * Wim + xq) = o;
    }
}

// ---------------------------------------------------------------------------
// K6 v3: fused epilogue GEMM + spatial-gate MLP, + T14 register prefetch of
// the next k-step's A columns (raw values; per-token sigmoid scale applied
// at LDS-write time, so the phase0->phase1 prefetch is legal before the
// gate is computed).
// ---------------------------------------------------------------------------
__global__ __launch_bounds__(256, 2) void k_final_mfma(const float* __restrict__ vbuf,
                                                       const float* __restrict__ convx,
                                                       const __bf16* __restrict__ Pt,
                                                       const float* __restrict__ si_w1,
                                                       const float* __restrict__ si_b1,
                                                       const float* __restrict__ bn3_g,
                                                       const float* __restrict__ bn3_b,
                                                       const float* __restrict__ bn3_m,
                                                       const float* __restrict__ bn3_v,
                                                       const float* __restrict__ si_w2,
                                                       const float* __restrict__ si_b2,
                                                       const float* __restrict__ proj_b,
                                                       float* __restrict__ out)
{
    __shared__ __align__(16) __bf16 Ah[128 * 40];
    __shared__ __align__(16) __bf16 Al[128 * 40];
    __shared__ __align__(16) __bf16 Bh[192 * 40];
    __shared__ __align__(16) __bf16 Bl[192 * 40];
    __shared__ float smbuf[128][17];
    __shared__ float ssp_s[128];

    const int t = threadIdx.x;
    const int lane = t & 63, wave = t >> 6;
    const int n0 = blockIdx.x * 128;
    const int b = blockIdx.y;
    const int row_base = (wave & 1) * 64;
    const int col_base = (wave >> 1) * 96;
    const int m16 = lane & 15, q = lane >> 4;

    const int an = t & 127;            // A-staging: token
    const int akh = (t >> 7) & 1;      // A-staging: 16-ch half
    const __bf16* ptb = Pt + (size_t)b * (2 * 73728);

    f32x4 acc[4][6];
#pragma unroll
    for (int rt = 0; rt < 4; ++rt)
#pragma unroll
        for (int ct = 0; ct < 6; ++ct)
#pragma unroll
            for (int j = 0; j < 4; ++j) acc[rt][ct][j] = 0.f;
    f32x4 accS[4];
#pragma unroll
    for (int rt = 0; rt < 4; ++rt)
#pragma unroll
        for (int j = 0; j < 4; ++j) accS[rt][j] = 0.f;

    float xv[16];
    auto loadA = [&](int ph, int ki2) {
        const int ch0 = ki2 * 32 + akh * 16;
        const float* src = (ph == 0)
            ? convx + ((size_t)b * Cc + ch0) * Ntok + n0 + an
            : vbuf + ((size_t)b * Cc + ch0) * Ntok + n0 + an;
#pragma unroll
        for (int jj = 0; jj < 16; ++jj)
            xv[jj] = src[(size_t)jj * Ntok];
    };
    loadA(0, 0);   // preload phase0, ki0

    for (int phase = 0; phase < 2; ++phase) {
        if (phase == 1) {
#pragma unroll
            for (int rt = 0; rt < 4; ++rt) {
                int row = row_base + rt * 16 + q * 4;
#pragma unroll
                for (int j = 0; j < 4; ++j)
                    smbuf[row + j][m16] = accS[rt][j];
            }
            __syncthreads();
            if (t < 128) {
                float sp = si_b2[0];
#pragma unroll
                for (int o = 0; o < 12; ++o) {
                    float z = smbuf[t][o] + si_b1[o];
                    float sc = bn3_g[o] / sqrtf(bn3_v[o] + EPSBN);
                    z = z * sc + (bn3_b[o] - bn3_m[o] * sc);
                    sp = fmaf(si_w2[o], gelu_f(z), sp);
                }
                ssp_s[t] = sigmoid_f(sp);
            }
            __syncthreads();
        }
        for (int ki = 0; ki < 6; ++ki) {
            const int kc = (phase == 0) ? (ki + 6) : ki;
            // ---- stage A from prefetched regs (apply gate scale here) ----
            {
                const float scale = (phase == 0) ? 1.f : ssp_s[an];
                float sv[16];
#pragma unroll
                for (int jj = 0; jj < 16; ++jj) sv[jj] = xv[jj] * scale;
                bf16x8 vh0, vl0, vh1, vl1;
                split8(sv, vh0, vl0);
                split8(sv + 8, vh1, vl1);
                const int o = an * 40 + akh * 16;
                *(bf16x8*)&Ah[o] = vh0; *(bf16x8*)&Ah[o + 8] = vh1;
                *(bf16x8*)&Al[o] = vl0; *(bf16x8*)&Al[o + 8] = vl1;
            }
            // ---- stage B from pre-split planes ----
#pragma unroll
            for (int i = 0; i < 3; ++i) {
                int f = i * 256 + t;
                int col = f >> 2, k8 = (f & 3) << 3;
                const __bf16* sp = ptb + (size_t)col * 384 + kc * 32 + k8;
                bf16x8 vh = *(const bf16x8*)sp;
                bf16x8 vl = *(const bf16x8*)(sp + 73728);
                *(bf16x8*)&Bh[col * 40 + k8] = vh;
                *(bf16x8*)&Bl[col * 40 + k8] = vl;
            }
            // ---- prefetch next A (flies across barriers) ----
            if (ki < 5) loadA(phase, ki + 1);
            else if (phase == 0) loadA(1, 0);
            __syncthreads();

            bf16x8 fah[4], fal[4], fbh[6], fbl[6];
#pragma unroll
            for (int rt = 0; rt < 4; ++rt) {
                int o = (row_base + rt * 16 + m16) * 40 + q * 8;
                fah[rt] = *(const bf16x8*)&Ah[o];
                fal[rt] = *(const bf16x8*)&Al[o];
            }
#pragma unroll
            for (int ct = 0; ct < 6; ++ct) {
                int o = (col_base + ct * 16 + m16) * 40 + q * 8;
                fbh[ct] = *(const bf16x8*)&Bh[o];
            }
#pragma unroll
            for (int rt = 0; rt < 4; ++rt)
#pragma unroll
                for (int ct = 0; ct < 6; ++ct) {
                    acc[rt][ct] = __builtin_amdgcn_mfma_f32_16x16x32_bf16(
                        fah[rt], fbh[ct], acc[rt][ct], 0, 0, 0);
                    acc[rt][ct] = __builtin_amdgcn_mfma_f32_16x16x32_bf16(
                        fal[rt], fbh[ct], acc[rt][ct], 0, 0, 0);
                }
#pragma unroll
            for (int ct = 0; ct < 6; ++ct) {
                int o = (col_base + ct * 16 + m16) * 40 + q * 8;
                fbl[ct] = *(const bf16x8*)&Bl[o];
            }
#pragma unroll
            for (int rt = 0; rt < 4; ++rt)
#pragma unroll
                for (int ct = 0; ct < 6; ++ct)
                    acc[rt][ct] = __builtin_amdgcn_mfma_f32_16x16x32_bf16(
                        fah[rt], fbl[ct], acc[rt][ct], 0, 0, 0);

            if (phase == 0) {
                bf16x8 w1h, w1l;
                if (m16 < 12) {
                    const float* wp = si_w1 + m16 * 192 + ki * 32 + q * 8;
                    float wv[8];
                    float4 u0 = *(const float4*)wp, u1 = *(const float4*)(wp + 4);
                    wv[0] = u0.x; wv[1] = u0.y; wv[2] = u0.z; wv[3] = u0.w;
                    wv[4] = u1.x; wv[5] = u1.y; wv[6] = u1.z; wv[7] = u1.w;
                    split8(wv, w1h, w1l);
                } else {
#pragma unroll
                    for (int j = 0; j < 8; ++j) { w1h[j] = (__bf16)0.f; w1l[j] = (__bf16)0.f; }
                }
#pragma unroll
                for (int rt = 0; rt < 4; ++rt) {
                    accS[rt] = __builtin_amdgcn_mfma_f32_16x16x32_bf16(
                        fah[rt], w1h, accS[rt], 0, 0, 0);
                    accS[rt] = __builtin_amdgcn_mfma_f32_16x16x32_bf16(
                        fal[rt], w1h, accS[rt], 0, 0, 0);
                    accS[rt] = __builtin_amdgcn_mfma_f32_16x16x32_bf16(
                        fah[rt], w1l, accS[rt], 0, 0, 0);
                }
            }
            __syncthreads();
        }
    }

    // ---- epilogue: out (B,N,C) token-major + proj_b ----
    float* ob = out + ((size_t)b * Ntok + n0) * Cc;
#pragma unroll
    for (int ct = 0; ct < 6; ++ct) {
        const int col = col_base + ct * 16 + m16;
        const float pbv = proj_b[col];
#pragma unroll
        for (int rt = 0; rt < 4; ++rt) {
            const int row = row_base + rt * 16 + q * 4;
#pragma unroll
            for (int j = 0; j < 4; ++j)
                ob[(size_t)(row + j) * Cc + col] = acc[rt][ct][j] + pbv;
        }
    }
}

extern "C" void kernel_launch(void* const* d_in, const int* in_sizes, int n_in,
                              void* d_out, int out_size, void* d_ws, size_t ws_size,
                              hipStream_t stream)
{
    const float* x      = (const float*)d_in[0];
    const float* w_qkv  = (const float*)d_in[3];
    const float* temperature = (const float*)d_in[4];
    const float* dw_w   = (const float*)d_in[5];
    const float* dw_b   = (const float*)d_in[6];
    const float* bn1_g  = (const float*)d_in[7];
    const float* bn1_b  = (const float*)d_in[8];
    const float* bn1_m  = (const float*)d_in[9];
    const float* bn1_v  = (const float*)d_in[10];
    const float* ci_w1  = (const float*)d_in[11];
    const float* ci_b1  = (const float*)d_in[12];
    const float* bn2_g  = (const float*)d_in[13];
    const float* bn2_b  = (const float*)d_in[14];
    const float* bn2_m  = (const float*)d_in[15];
    const float* bn2_v  = (const float*)d_in[16];
    const float* ci_w2  = (const float*)d_in[17];
    const float* ci_b2  = (const float*)d_in[18];
    const float* si_w1  = (const float*)d_in[19];
    const float* si_b1  = (const float*)d_in[20];
    const float* bn3_g  = (const float*)d_in[21];
    const float* bn3_b  = (const float*)d_in[22];
    const float* bn3_m  = (const float*)d_in[23];
    const float* bn3_v  = (const float*)d_in[24];
    const float* si_w2  = (const float*)d_in[25];
    const float* si_b2  = (const float*)d_in[26];
    const float* proj_w = (const float*)d_in[27];
    const float* proj_b = (const float*)d_in[28];

    float* ws = (float*)d_ws;
    const size_t BCN = (size_t)Bb * Cc * Ntok;      // 25,165,824
    float* vbuf  = ws;
    float* convx = ws + BCN;
    __bf16* Pt   = (__bf16*)(ws + 2 * BCN);         // 8*2*73728 bf16 = 589824 f
    float* xpart = ws + 2 * BCN + 589824;           // 256*36864 = 9,437,184
    float* XtX   = xpart + 9437184;                 // 294,912
    float* gram  = XtX + 294912;                    // 36864
    float* ssq_q = gram + 36864;                    // 1536
    float* ssq_k = ssq_q + 1536;                    // 1536
    float* vmean = ssq_k + 1536;                    // 1536 (holds channel SUMS)
    float* attn  = vmean + 1536;                    // 36864
    float* sig_ch = attn + 36864;                   // 1536
    float* out = (float*)d_out;

    __bf16* wt = (__bf16*)(out + BCN - 36864);      // 73728 bf16 in out tail

    hipMemsetAsync(vmean, 0, 1536 * sizeof(float), stream);

    k_wprep<<<dim3(144), 256, 0, stream>>>(w_qkv, wt);
    k_xtx<<<dim3(32, Bb), 512, 0, stream>>>(x, xpart);
    k_xred<<<dim3(144, Bb), 256, 0, stream>>>(xpart, XtX);
    k_gram2<<<dim3(Bb, NHEADS), 256, 0, stream>>>(XtX, w_qkv, gram, ssq_q, ssq_k);
    k_qkv_mfma<<<dim3(Ntok / 128, Bb), 256, 0, stream>>>(x, wt, vbuf, vmean);
    k_attn<<<dim3(Bb), 256, 0, stream>>>(gram, ssq_q, ssq_k, temperature, vmean,
                                         ci_w1, ci_b1, bn2_g, bn2_b, bn2_m, bn2_v,
                                         ci_w2, ci_b2, attn, sig_ch);
    k_pprep<<<dim3(Bb, 9), 192, 0, stream>>>(attn, sig_ch, proj_w, Pt);
    k_conv<<<dim3(Him / 8, Cc / 8, Bb), 256, 0, stream>>>(
        vbuf, dw_w, dw_b, bn1_g, bn1_b, bn1_m, bn1_v, convx);
    k_final_mfma<<<dim3(Ntok / 128, Bb), 256, 0, stream>>>(
        vbuf, convx, Pt, si_w1, si_b1, bn3_g, bn3_b, bn3_m, bn3_v,
        si_w2, si_b2, proj_b, out);
}